// Round 4
// baseline (1103.364 us; speedup 1.0000x reference)
//
#include <hip/hip_runtime.h>
#include <math.h>

#define B_   4
#define L_   512
#define DM_  1024
#define DS_  16
#define DC_  4
#define DI_  2048
#define DTR_ 64

typedef unsigned short ushort_t;
typedef __attribute__((ext_vector_type(8))) short short8v;
typedef __attribute__((ext_vector_type(4))) float f32x4;

__device__ __forceinline__ ushort_t f2bf(float f) {
    unsigned u = __float_as_uint(f);
    return (ushort_t)((u + 0x7fffu + ((u >> 16) & 1u)) >> 16);
}
__device__ __forceinline__ float bf2f(ushort_t h) {
    return __uint_as_float((unsigned)h << 16);
}

// ---------------------------------------------------------------------------
// Batched fp32 -> (hi, lo) bf16 plane conversion: 7 segments in one launch.
// ---------------------------------------------------------------------------
#define NSEG 7
struct CvtArgs {
    const float* src[NSEG];
    ushort_t*    hi[NSEG];
    ushort_t*    lo[NSEG];
    int start4[NSEG];   // prefix offsets in quads
    int total4;
};

__global__ __launch_bounds__(256)
void cvt_multi(CvtArgs a)
{
    const int i = blockIdx.x * 256 + threadIdx.x;
    if (i >= a.total4) return;
    int s = 0;
    #pragma unroll
    for (int k = 1; k < NSEG; k++) s += (i >= a.start4[k]) ? 1 : 0;
    const int j = i - a.start4[s];

    const float4 v = ((const float4*)a.src[s])[j];
    const ushort_t h0 = f2bf(v.x), h1 = f2bf(v.y), h2 = f2bf(v.z), h3 = f2bf(v.w);
    ((uint2*)a.hi[s])[j] = make_uint2(h0 | ((unsigned)h1 << 16), h2 | ((unsigned)h3 << 16));
    const ushort_t l0 = f2bf(v.x - bf2f(h0)), l1 = f2bf(v.y - bf2f(h1));
    const ushort_t l2 = f2bf(v.z - bf2f(h2)), l3 = f2bf(v.w - bf2f(h3));
    ((uint2*)a.lo[s])[j] = make_uint2(l0 | ((unsigned)l1 << 16), l2 | ((unsigned)l3 << 16));
}

// ---------------------------------------------------------------------------
// Split-bf16 MFMA GEMM: C[M,N] = A[M,K] @ W[N,K]^T, A/W given as hi/lo planes.
// 128x128 tile, BK=32, 4 waves of 64x64. M multiple of 128, K multiple of 32.
// EPI: 0 none, 1 bias+softplus, 2 bias+leakyrelu, 3 bias.
// Outputs: optional fp32 C and/or hi/lo bf16 planes (same layout).
// ---------------------------------------------------------------------------
template<int EPI>
__global__ __launch_bounds__(256, 2)
void gemm_mfma(const ushort_t* __restrict__ Ahi, const ushort_t* __restrict__ Alo, int lda,
               const ushort_t* __restrict__ Whi, const ushort_t* __restrict__ Wlo, int ldw,
               const float* __restrict__ bias,
               float* __restrict__ C, ushort_t* __restrict__ Chi, ushort_t* __restrict__ Clo,
               int ldc, int N, int K)
{
    __shared__ ushort_t lds[4][4][128][8];   // [plane Ah,Al,Bh,Bl][kchunk][row][8]

    const int t    = threadIdx.x;
    const int lane = t & 63;
    const int wv   = t >> 6;
    const int wm   = (wv >> 1) * 64;
    const int wn   = (wv & 1) * 64;
    const int m0   = blockIdx.y * 128;
    const int n0   = blockIdx.x * 128;
    const int fr   = lane & 15;
    const int fc   = lane >> 4;

    // staging: wave wv owns plane wv (0=Ah 1=Al 2=Wh 3=Wl)
    const ushort_t* gbase = (wv == 0) ? Ahi : (wv == 1) ? Alo : (wv == 2) ? Whi : Wlo;
    const int grow0 = ((wv < 2) ? m0 : n0) + lane;
    const int gld   = (wv < 2) ? lda : ldw;

    f32x4 acc[4][4];
    #pragma unroll
    for (int i = 0; i < 4; i++)
        #pragma unroll
        for (int j = 0; j < 4; j++)
            acc[i][j] = (f32x4){0.f, 0.f, 0.f, 0.f};

    for (int k0 = 0; k0 < K; k0 += 32) {
        __syncthreads();   // previous tile's reads done before overwrite
        #pragma unroll
        for (int s = 0; s < 8; s++) {
            const int c = s >> 1, half = s & 1;
            const ushort_t* g = gbase + (size_t)(grow0 + half * 64) * gld + (k0 + c * 8);
            const ushort_t* l = &lds[wv][c][half * 64][0];
            __builtin_amdgcn_global_load_lds(
                (const __attribute__((address_space(1))) void*)g,
                (__attribute__((address_space(3))) void*)l, 16, 0, 0);
        }
        __syncthreads();   // drains vmcnt + barrier

        short8v ah[4], al[4];
        #pragma unroll
        for (int i = 0; i < 4; i++) {
            ah[i] = *(const short8v*)&lds[0][fc][wm + i * 16 + fr][0];
            al[i] = *(const short8v*)&lds[1][fc][wm + i * 16 + fr][0];
        }
        #pragma unroll
        for (int j = 0; j < 4; j++) {
            const short8v bh = *(const short8v*)&lds[2][fc][wn + j * 16 + fr][0];
            const short8v bl = *(const short8v*)&lds[3][fc][wn + j * 16 + fr][0];
            #pragma unroll
            for (int i = 0; i < 4; i++) {
                acc[i][j] = __builtin_amdgcn_mfma_f32_16x16x32_bf16(al[i], bh, acc[i][j], 0, 0, 0);
                acc[i][j] = __builtin_amdgcn_mfma_f32_16x16x32_bf16(ah[i], bl, acc[i][j], 0, 0, 0);
                acc[i][j] = __builtin_amdgcn_mfma_f32_16x16x32_bf16(ah[i], bh, acc[i][j], 0, 0, 0);
            }
        }
    }

    // epilogue: D row = (lane>>4)*4 + reg, col = lane&15  [m89-verified]
    #pragma unroll
    for (int j = 0; j < 4; j++) {
        const int c = n0 + wn + j * 16 + fr;
        float bj = 0.f;
        if (EPI != 0) bj = bias[c];          // EPI!=0 only used with N%128==0
        if (c < N) {
            #pragma unroll
            for (int i = 0; i < 4; i++) {
                const int r = m0 + wm + i * 16 + fc * 4;
                #pragma unroll
                for (int q = 0; q < 4; q++) {
                    float v = acc[i][j][q] + bj;
                    if (EPI == 1) v = fmaxf(v, 0.f) + log1pf(expf(-fabsf(v)));
                    else if (EPI == 2) v = (v >= 0.f) ? v : 0.01f * v;
                    const size_t idx = (size_t)(r + q) * ldc + c;
                    if (C) C[idx] = v;
                    if (Chi) {
                        const ushort_t h = f2bf(v);
                        Chi[idx] = h;
                        Clo[idx] = f2bf(v - bf2f(h));
                    }
                }
            }
        }
    }
}

// ---------------------------------------------------------------------------
// Depthwise causal conv (DC=4) + bias + SiLU; emits fp32 + hi/lo bf16.
// 4 channels per thread.
// ---------------------------------------------------------------------------
__global__ __launch_bounds__(256)
void conv_silu_kernel(const float* __restrict__ xz,
                      const float* __restrict__ cw,
                      const float* __restrict__ cb,
                      float* __restrict__ xs,
                      ushort_t* __restrict__ xsh, ushort_t* __restrict__ xsl)
{
    const int g   = blockIdx.x * 256 + threadIdx.x;   // quad id
    const int d   = (g & (DI_ / 4 - 1)) * 4;
    const int tok = g >> 9;
    const int l   = tok & (L_ - 1);
    const int t0  = tok - l;
    const float4 w0 = *(const float4*)&cw[(d + 0) * 4];
    const float4 w1 = *(const float4*)&cw[(d + 1) * 4];
    const float4 w2 = *(const float4*)&cw[(d + 2) * 4];
    const float4 w3 = *(const float4*)&cw[(d + 3) * 4];
    float4 s = *(const float4*)&cb[d];
    if (l >= 3) { const float4 v = *(const float4*)&xz[(size_t)(t0 + l - 3) * (2 * DI_) + d];
        s.x += w0.x * v.x; s.y += w1.x * v.y; s.z += w2.x * v.z; s.w += w3.x * v.w; }
    if (l >= 2) { const float4 v = *(const float4*)&xz[(size_t)(t0 + l - 2) * (2 * DI_) + d];
        s.x += w0.y * v.x; s.y += w1.y * v.y; s.z += w2.y * v.z; s.w += w3.y * v.w; }
    if (l >= 1) { const float4 v = *(const float4*)&xz[(size_t)(t0 + l - 1) * (2 * DI_) + d];
        s.x += w0.z * v.x; s.y += w1.z * v.y; s.z += w2.z * v.z; s.w += w3.z * v.w; }
    {           const float4 v = *(const float4*)&xz[(size_t)(t0 + l) * (2 * DI_) + d];
        s.x += w0.w * v.x; s.y += w1.w * v.y; s.z += w2.w * v.z; s.w += w3.w * v.w; }
    s.x = s.x / (1.f + __expf(-s.x));
    s.y = s.y / (1.f + __expf(-s.y));
    s.z = s.z / (1.f + __expf(-s.z));
    s.w = s.w / (1.f + __expf(-s.w));
    const size_t off = (size_t)tok * DI_ + d;
    *(float4*)&xs[off] = s;
    const ushort_t h0 = f2bf(s.x), h1 = f2bf(s.y), h2 = f2bf(s.z), h3 = f2bf(s.w);
    *(uint2*)&xsh[off] = make_uint2(h0 | ((unsigned)h1 << 16), h2 | ((unsigned)h3 << 16));
    const ushort_t l0 = f2bf(s.x - bf2f(h0)), l1 = f2bf(s.y - bf2f(h1));
    const ushort_t l2 = f2bf(s.z - bf2f(h2)), l3 = f2bf(s.w - bf2f(h3));
    *(uint2*)&xsl[off] = make_uint2(l0 | ((unsigned)l1 << 16), l2 | ((unsigned)l3 << 16));
}

// ---------------------------------------------------------------------------
// Selective scan: one lane per (b, d, n). 16 lanes (n) reduce via shfl.
// Block = 256 threads = 16 d x 16 n. Emits y as hi/lo bf16 planes.
// ---------------------------------------------------------------------------
__global__ __launch_bounds__(256)
void scan_kernel(const float* __restrict__ dt,     // (B,L,DI) post-softplus
                 const float* __restrict__ xs,     // (B,L,DI)
                 const float* __restrict__ xdbl,   // (B,L,96)
                 const float* __restrict__ xz,     // z at col DI_+d
                 const float* __restrict__ A_log,
                 const float* __restrict__ Dp,
                 ushort_t* __restrict__ yh, ushort_t* __restrict__ yl)
{
    const int tid  = threadIdx.x;
    const int n    = tid & 15;
    const int dloc = tid >> 4;                   // 0..15
    const int b    = blockIdx.x / (DI_ / 16);
    const int d0   = (blockIdx.x % (DI_ / 16)) * 16;
    const int d    = d0 + dloc;
    const int lane = tid & 63;
    const int w    = tid >> 6;

    const float a  = -expf(A_log[d * DS_ + n]);   // A = -exp(A_log)
    const float Dd = Dp[d];

    float h = 0.f;
    size_t tok = (size_t)b * L_;
    float dtv = dt[tok * DI_ + d];
    float xv  = xs[tok * DI_ + d];
    float Bn  = xdbl[tok * 96 + 64 + n];
    float Cn  = xdbl[tok * 96 + 80 + n];
    float zv  = xz[tok * (2 * DI_) + DI_ + d];

    #pragma unroll 1
    for (int l = 0; l < L_; l++) {
        float ndtv = 0.f, nxv = 0.f, nBn = 0.f, nCn = 0.f, nzv = 0.f;
        if (l + 1 < L_) {
            const size_t t2 = tok + 1;
            ndtv = dt[t2 * DI_ + d];
            nxv  = xs[t2 * DI_ + d];
            nBn  = xdbl[t2 * 96 + 64 + n];
            nCn  = xdbl[t2 * 96 + 80 + n];
            nzv  = xz[t2 * (2 * DI_) + DI_ + d];
        }
        h = fmaf(__expf(dtv * a), h, dtv * xv * Bn);
        float p = h * Cn;
        p += __shfl_xor(p, 8, 16);
        p += __shfl_xor(p, 4, 16);
        p += __shfl_xor(p, 2, 16);
        p += __shfl_xor(p, 1, 16);
        const float sz = zv / (1.f + __expf(-zv));
        const float yv = fmaf(Dd, xv, p) * sz;
        const float o  = __shfl(yv, (lane & 3) << 4, 64);
        if (lane < 4) {
            const size_t idx = tok * DI_ + d0 + w * 4 + lane;
            const ushort_t hh = f2bf(o);
            yh[idx] = hh;
            yl[idx] = f2bf(o - bf2f(hh));
        }
        tok++;
        dtv = ndtv; xv = nxv; Bn = nBn; Cn = nCn; zv = nzv;
    }
}

// ---------------------------------------------------------------------------
// out = LN(a + r) * w + b ; optional hi/lo bf16 planes. One block per token.
// ---------------------------------------------------------------------------
__global__ __launch_bounds__(256)
void ln_kernel(const float* __restrict__ a, const float* __restrict__ r,
               const float* __restrict__ w, const float* __restrict__ b,
               float* __restrict__ out,
               ushort_t* __restrict__ oh, ushort_t* __restrict__ ol)
{
    const int tok = blockIdx.x;
    const int tid = threadIdx.x;
    const size_t off = (size_t)tok * DM_ + tid * 4;
    const float4 va = *(const float4*)&a[off];
    const float4 vr = *(const float4*)&r[off];
    const float xv[4] = {va.x + vr.x, va.y + vr.y, va.z + vr.z, va.w + vr.w};

    float s  = xv[0] + xv[1] + xv[2] + xv[3];
    float sq = xv[0]*xv[0] + xv[1]*xv[1] + xv[2]*xv[2] + xv[3]*xv[3];
    #pragma unroll
    for (int o = 32; o > 0; o >>= 1) {
        s  += __shfl_xor(s,  o, 64);
        sq += __shfl_xor(sq, o, 64);
    }
    __shared__ float ss[4], sqs[4];
    const int wid = tid >> 6;
    if ((tid & 63) == 0) { ss[wid] = s; sqs[wid] = sq; }
    __syncthreads();
    s  = ss[0] + ss[1] + ss[2] + ss[3];
    sq = sqs[0] + sqs[1] + sqs[2] + sqs[3];

    const float mean = s * (1.f / DM_);
    const float var  = sq * (1.f / DM_) - mean * mean;
    const float rs   = rsqrtf(var + 1e-12f);

    const float4 vw = *(const float4*)&w[tid * 4];
    const float4 vb = *(const float4*)&b[tid * 4];
    const float o0 = (xv[0] - mean) * rs * vw.x + vb.x;
    const float o1 = (xv[1] - mean) * rs * vw.y + vb.y;
    const float o2 = (xv[2] - mean) * rs * vw.z + vb.z;
    const float o3 = (xv[3] - mean) * rs * vw.w + vb.w;
    *(float4*)&out[off] = make_float4(o0, o1, o2, o3);
    if (oh) {
        const ushort_t h0 = f2bf(o0), h1 = f2bf(o1), h2 = f2bf(o2), h3 = f2bf(o3);
        *(uint2*)&oh[off] = make_uint2(h0 | ((unsigned)h1 << 16), h2 | ((unsigned)h3 << 16));
        const ushort_t l0 = f2bf(o0 - bf2f(h0)), l1 = f2bf(o1 - bf2f(h1));
        const ushort_t l2 = f2bf(o2 - bf2f(h2)), l3 = f2bf(o3 - bf2f(h3));
        *(uint2*)&ol[off] = make_uint2(l0 | ((unsigned)l1 << 16), l2 | ((unsigned)l3 << 16));
    }
}

// ---------------------------------------------------------------------------
extern "C" void kernel_launch(void* const* d_in, const int* in_sizes, int n_in,
                              void* d_out, int out_size, void* d_ws, size_t ws_size,
                              hipStream_t stream)
{
    const float* x        = (const float*)d_in[0];
    const float* in_w     = (const float*)d_in[1];
    const float* conv_w   = (const float*)d_in[2];
    const float* conv_b   = (const float*)d_in[3];
    const float* xproj_w  = (const float*)d_in[4];
    const float* dtproj_w = (const float*)d_in[5];
    const float* dtproj_b = (const float*)d_in[6];
    const float* A_log    = (const float*)d_in[7];
    const float* Dp       = (const float*)d_in[8];
    const float* outw     = (const float*)d_in[9];
    const float* ln1w     = (const float*)d_in[10];
    const float* ln1b     = (const float*)d_in[11];
    const float* fw1      = (const float*)d_in[12];
    const float* fb1      = (const float*)d_in[13];
    const float* fw2      = (const float*)d_in[14];
    const float* fb2      = (const float*)d_in[15];
    const float* ln2w     = (const float*)d_in[16];
    const float* ln2b     = (const float*)d_in[17];
    float* out = (float*)d_out;

    const int M = B_ * L_;   // 2048
    // ---- workspace carve (floats). total ~42.8M floats ~171 MB ----
    float* p = (float*)d_ws;
    float* xz     = p; p += (size_t)M * 4096;          // fp32
    float* xsact  = p; p += (size_t)M * 2048;          // fp32
    float* xsact_h= p; p += (size_t)M * 2048 / 2;      // bf16 plane (also hres planes later)
    float* xsact_l= p; p += (size_t)M * 2048 / 2;
    float* xdbl   = p; p += (size_t)M * 96;
    float* xdbl_h = p; p += (size_t)M * 96 / 2;
    float* xdbl_l = p; p += (size_t)M * 96 / 2;
    float* dtb    = p; p += (size_t)M * 2048;
    float* y_h    = p; p += (size_t)M * 2048 / 2;      // also f1 planes later
    float* y_l    = p; p += (size_t)M * 2048 / 2;
    float* mo     = p; p += (size_t)M * 1024;
    float* hres   = p; p += (size_t)M * 1024;
    float* x_h    = p; p += (size_t)M * 1024 / 2;
    float* x_l    = p; p += (size_t)M * 1024 / 2;
    float* inw_h  = p; p += (size_t)4096 * 1024 / 2;
    float* inw_l  = p; p += (size_t)4096 * 1024 / 2;
    float* xpw_h  = p; p += (size_t)128 * 2048 / 2;    // 96 rows used, padded to 128
    float* xpw_l  = p; p += (size_t)128 * 2048 / 2;
    float* dtw_h  = p; p += (size_t)2048 * 64 / 2;
    float* dtw_l  = p; p += (size_t)2048 * 64 / 2;
    float* ow_h   = p; p += (size_t)1024 * 2048 / 2;
    float* ow_l   = p; p += (size_t)1024 * 2048 / 2;
    float* f1w_h  = p; p += (size_t)2048 * 1024 / 2;
    float* f1w_l  = p; p += (size_t)2048 * 1024 / 2;
    float* f2w_h  = p; p += (size_t)1024 * 2048 / 2;
    float* f2w_l  = p; p += (size_t)1024 * 2048 / 2;

    ushort_t* h_h  = (ushort_t*)xsact_h;   // overlay: xsact planes dead after x_proj
    ushort_t* h_l  = (ushort_t*)xsact_l;
    ushort_t* f1_h = (ushort_t*)y_h;       // overlay: y planes dead after out_proj
    ushort_t* f1_l = (ushort_t*)y_l;

    const dim3 blk(256);

    // ---- single batched conversion launch (7 segments) ----
    CvtArgs ca;
    const float* srcs[NSEG] = {x, in_w, xproj_w, dtproj_w, outw, fw1, fw2};
    ushort_t* his[NSEG] = {(ushort_t*)x_h, (ushort_t*)inw_h, (ushort_t*)xpw_h,
                           (ushort_t*)dtw_h, (ushort_t*)ow_h, (ushort_t*)f1w_h,
                           (ushort_t*)f2w_h};
    ushort_t* los[NSEG] = {(ushort_t*)x_l, (ushort_t*)inw_l, (ushort_t*)xpw_l,
                           (ushort_t*)dtw_l, (ushort_t*)ow_l, (ushort_t*)f1w_l,
                           (ushort_t*)f2w_l};
    const int n4s[NSEG] = {M * 1024 / 4, 4096 * 1024 / 4, 96 * 2048 / 4,
                           2048 * 64 / 4, 1024 * 2048 / 4, 2048 * 1024 / 4,
                           1024 * 2048 / 4};
    int acc4 = 0;
    for (int s = 0; s < NSEG; s++) {
        ca.src[s] = srcs[s]; ca.hi[s] = his[s]; ca.lo[s] = los[s];
        ca.start4[s] = acc4; acc4 += n4s[s];
    }
    ca.total4 = acc4;
    cvt_multi<<<dim3((acc4 + 255) / 256), blk, 0, stream>>>(ca);

    // 1. in_proj: xz = x @ in_w^T   (2048 x 4096 x 1024)
    gemm_mfma<0><<<dim3(32, 16), blk, 0, stream>>>(
        (ushort_t*)x_h, (ushort_t*)x_l, 1024,
        (ushort_t*)inw_h, (ushort_t*)inw_l, 1024,
        nullptr, xz, nullptr, nullptr, 4096, 4096, 1024);
    // 2. conv + silu (emits fp32 + planes)
    conv_silu_kernel<<<dim3(M * DI_ / 4 / 256), blk, 0, stream>>>(
        xz, conv_w, conv_b, xsact, (ushort_t*)xsact_h, (ushort_t*)xsact_l);
    // 3. x_proj: xdbl (2048 x 96 x 2048), fp32 + planes
    gemm_mfma<0><<<dim3(1, 16), blk, 0, stream>>>(
        (ushort_t*)xsact_h, (ushort_t*)xsact_l, 2048,
        (ushort_t*)xpw_h, (ushort_t*)xpw_l, 2048,
        nullptr, xdbl, (ushort_t*)xdbl_h, (ushort_t*)xdbl_l, 96, 96, 2048);
    // 4. dt = softplus(dt_r @ dt_w^T + b)  (2048 x 2048 x 64)
    gemm_mfma<1><<<dim3(16, 16), blk, 0, stream>>>(
        (ushort_t*)xdbl_h, (ushort_t*)xdbl_l, 96,
        (ushort_t*)dtw_h, (ushort_t*)dtw_l, 64,
        dtproj_b, dtb, nullptr, nullptr, 2048, 2048, 64);
    // 5. scan (emits y planes)
    scan_kernel<<<dim3(B_ * DI_ / 16), blk, 0, stream>>>(
        dtb, xsact, xdbl, xz, A_log, Dp, (ushort_t*)y_h, (ushort_t*)y_l);
    // 6. out_proj: mo (2048 x 1024 x 2048)
    gemm_mfma<0><<<dim3(8, 16), blk, 0, stream>>>(
        (ushort_t*)y_h, (ushort_t*)y_l, 2048,
        (ushort_t*)ow_h, (ushort_t*)ow_l, 2048,
        nullptr, mo, nullptr, nullptr, 1024, 1024, 2048);
    // 7. hres = LN1(mo + x)  (+ planes)
    ln_kernel<<<dim3(M), blk, 0, stream>>>(mo, x, ln1w, ln1b, hres, h_h, h_l);
    // 8. ffn1 + leakyrelu -> f1 planes only  (2048 x 2048 x 1024)
    gemm_mfma<2><<<dim3(16, 16), blk, 0, stream>>>(
        h_h, h_l, 1024,
        (ushort_t*)f1w_h, (ushort_t*)f1w_l, 1024,
        fb1, nullptr, f1_h, f1_l, 2048, 2048, 1024);
    // 9. ffn2 + bias -> mo  (2048 x 1024 x 2048)
    gemm_mfma<3><<<dim3(8, 16), blk, 0, stream>>>(
        f1_h, f1_l, 2048,
        (ushort_t*)f2w_h, (ushort_t*)f2w_l, 2048,
        fb2, mo, nullptr, nullptr, 1024, 1024, 2048);
    // 10. out = LN2(mo + hres)
    ln_kernel<<<dim3(M), blk, 0, stream>>>(mo, hres, ln2w, ln2b, out, nullptr, nullptr);
}

// Round 5
// 883.975 us; speedup vs baseline: 1.2482x; 1.2482x over previous
//
#include <hip/hip_runtime.h>
#include <math.h>

#define B_   4
#define L_   512
#define DM_  1024
#define DS_  16
#define DC_  4
#define DI_  2048
#define DTR_ 64
#define NCH_ 16
#define CHL_ 32   // L_ / NCH_

typedef unsigned short ushort_t;
typedef __attribute__((ext_vector_type(8))) short short8v;
typedef __attribute__((ext_vector_type(4))) float f32x4;

__device__ __forceinline__ ushort_t f2bf(float f) {
    unsigned u = __float_as_uint(f);
    return (ushort_t)((u + 0x7fffu + ((u >> 16) & 1u)) >> 16);
}
__device__ __forceinline__ float bf2f(ushort_t h) {
    return __uint_as_float((unsigned)h << 16);
}

// ---------------------------------------------------------------------------
// Batched fp32 -> (hi, lo) bf16 plane conversion: 7 segments in one launch.
// ---------------------------------------------------------------------------
#define NSEG 7
struct CvtArgs {
    const float* src[NSEG];
    ushort_t*    hi[NSEG];
    ushort_t*    lo[NSEG];
    int start4[NSEG];   // prefix offsets in quads
    int total4;
};

__global__ __launch_bounds__(256)
void cvt_multi(CvtArgs a)
{
    const int i = blockIdx.x * 256 + threadIdx.x;
    if (i >= a.total4) return;
    int s = 0;
    #pragma unroll
    for (int k = 1; k < NSEG; k++) s += (i >= a.start4[k]) ? 1 : 0;
    const int j = i - a.start4[s];

    const float4 v = ((const float4*)a.src[s])[j];
    const ushort_t h0 = f2bf(v.x), h1 = f2bf(v.y), h2 = f2bf(v.z), h3 = f2bf(v.w);
    ((uint2*)a.hi[s])[j] = make_uint2(h0 | ((unsigned)h1 << 16), h2 | ((unsigned)h3 << 16));
    const ushort_t l0 = f2bf(v.x - bf2f(h0)), l1 = f2bf(v.y - bf2f(h1));
    const ushort_t l2 = f2bf(v.z - bf2f(h2)), l3 = f2bf(v.w - bf2f(h3));
    ((uint2*)a.lo[s])[j] = make_uint2(l0 | ((unsigned)l1 << 16), l2 | ((unsigned)l3 << 16));
}

// ---------------------------------------------------------------------------
// Split-bf16 MFMA GEMM: C[M,N] = A[M,K] @ W[N,K]^T, A/W given as hi/lo planes.
// 128x128 tile, BK=32, 4 waves of 64x64. M multiple of 128, K multiple of 32.
// EPI: 0 none, 1 bias+softplus, 2 bias+leakyrelu, 3 bias.
// ---------------------------------------------------------------------------
template<int EPI>
__global__ __launch_bounds__(256, 2)
void gemm_mfma(const ushort_t* __restrict__ Ahi, const ushort_t* __restrict__ Alo, int lda,
               const ushort_t* __restrict__ Whi, const ushort_t* __restrict__ Wlo, int ldw,
               const float* __restrict__ bias,
               float* __restrict__ C, ushort_t* __restrict__ Chi, ushort_t* __restrict__ Clo,
               int ldc, int N, int K)
{
    __shared__ ushort_t lds[4][4][128][8];   // [plane Ah,Al,Bh,Bl][kchunk][row][8]

    const int t    = threadIdx.x;
    const int lane = t & 63;
    const int wv   = t >> 6;
    const int wm   = (wv >> 1) * 64;
    const int wn   = (wv & 1) * 64;
    const int m0   = blockIdx.y * 128;
    const int n0   = blockIdx.x * 128;
    const int fr   = lane & 15;
    const int fc   = lane >> 4;

    // staging: wave wv owns plane wv (0=Ah 1=Al 2=Wh 3=Wl)
    const ushort_t* gbase = (wv == 0) ? Ahi : (wv == 1) ? Alo : (wv == 2) ? Whi : Wlo;
    const int grow0 = ((wv < 2) ? m0 : n0) + lane;
    const int gld   = (wv < 2) ? lda : ldw;

    f32x4 acc[4][4];
    #pragma unroll
    for (int i = 0; i < 4; i++)
        #pragma unroll
        for (int j = 0; j < 4; j++)
            acc[i][j] = (f32x4){0.f, 0.f, 0.f, 0.f};

    for (int k0 = 0; k0 < K; k0 += 32) {
        __syncthreads();   // previous tile's reads done before overwrite
        #pragma unroll
        for (int s = 0; s < 8; s++) {
            const int c = s >> 1, half = s & 1;
            const ushort_t* g = gbase + (size_t)(grow0 + half * 64) * gld + (k0 + c * 8);
            const ushort_t* l = &lds[wv][c][half * 64][0];
            __builtin_amdgcn_global_load_lds(
                (const __attribute__((address_space(1))) void*)g,
                (__attribute__((address_space(3))) void*)l, 16, 0, 0);
        }
        __syncthreads();   // drains vmcnt + barrier

        short8v ah[4], al[4];
        #pragma unroll
        for (int i = 0; i < 4; i++) {
            ah[i] = *(const short8v*)&lds[0][fc][wm + i * 16 + fr][0];
            al[i] = *(const short8v*)&lds[1][fc][wm + i * 16 + fr][0];
        }
        #pragma unroll
        for (int j = 0; j < 4; j++) {
            const short8v bh = *(const short8v*)&lds[2][fc][wn + j * 16 + fr][0];
            const short8v bl = *(const short8v*)&lds[3][fc][wn + j * 16 + fr][0];
            #pragma unroll
            for (int i = 0; i < 4; i++) {
                acc[i][j] = __builtin_amdgcn_mfma_f32_16x16x32_bf16(al[i], bh, acc[i][j], 0, 0, 0);
                acc[i][j] = __builtin_amdgcn_mfma_f32_16x16x32_bf16(ah[i], bl, acc[i][j], 0, 0, 0);
                acc[i][j] = __builtin_amdgcn_mfma_f32_16x16x32_bf16(ah[i], bh, acc[i][j], 0, 0, 0);
            }
        }
    }

    // epilogue: D row = (lane>>4)*4 + reg, col = lane&15  [m89-verified]
    #pragma unroll
    for (int j = 0; j < 4; j++) {
        const int c = n0 + wn + j * 16 + fr;
        float bj = 0.f;
        if (EPI != 0) bj = bias[c];          // EPI!=0 only used with N%128==0
        if (c < N) {
            #pragma unroll
            for (int i = 0; i < 4; i++) {
                const int r = m0 + wm + i * 16 + fc * 4;
                #pragma unroll
                for (int q = 0; q < 4; q++) {
                    float v = acc[i][j][q] + bj;
                    if (EPI == 1) v = fmaxf(v, 0.f) + log1pf(expf(-fabsf(v)));
                    else if (EPI == 2) v = (v >= 0.f) ? v : 0.01f * v;
                    const size_t idx = (size_t)(r + q) * ldc + c;
                    if (C) C[idx] = v;
                    if (Chi) {
                        const ushort_t h = f2bf(v);
                        Chi[idx] = h;
                        Clo[idx] = f2bf(v - bf2f(h));
                    }
                }
            }
        }
    }
}

// ---------------------------------------------------------------------------
// Depthwise causal conv (DC=4) + bias + SiLU; emits fp32 + hi/lo bf16.
// ---------------------------------------------------------------------------
__global__ __launch_bounds__(256)
void conv_silu_kernel(const float* __restrict__ xz,
                      const float* __restrict__ cw,
                      const float* __restrict__ cb,
                      float* __restrict__ xs,
                      ushort_t* __restrict__ xsh, ushort_t* __restrict__ xsl)
{
    const int g   = blockIdx.x * 256 + threadIdx.x;   // quad id
    const int d   = (g & (DI_ / 4 - 1)) * 4;
    const int tok = g >> 9;
    const int l   = tok & (L_ - 1);
    const int t0  = tok - l;
    const float4 w0 = *(const float4*)&cw[(d + 0) * 4];
    const float4 w1 = *(const float4*)&cw[(d + 1) * 4];
    const float4 w2 = *(const float4*)&cw[(d + 2) * 4];
    const float4 w3 = *(const float4*)&cw[(d + 3) * 4];
    float4 s = *(const float4*)&cb[d];
    if (l >= 3) { const float4 v = *(const float4*)&xz[(size_t)(t0 + l - 3) * (2 * DI_) + d];
        s.x += w0.x * v.x; s.y += w1.x * v.y; s.z += w2.x * v.z; s.w += w3.x * v.w; }
    if (l >= 2) { const float4 v = *(const float4*)&xz[(size_t)(t0 + l - 2) * (2 * DI_) + d];
        s.x += w0.y * v.x; s.y += w1.y * v.y; s.z += w2.y * v.z; s.w += w3.y * v.w; }
    if (l >= 1) { const float4 v = *(const float4*)&xz[(size_t)(t0 + l - 1) * (2 * DI_) + d];
        s.x += w0.z * v.x; s.y += w1.z * v.y; s.z += w2.z * v.z; s.w += w3.z * v.w; }
    {           const float4 v = *(const float4*)&xz[(size_t)(t0 + l) * (2 * DI_) + d];
        s.x += w0.w * v.x; s.y += w1.w * v.y; s.z += w2.w * v.z; s.w += w3.w * v.w; }
    s.x = s.x / (1.f + __expf(-s.x));
    s.y = s.y / (1.f + __expf(-s.y));
    s.z = s.z / (1.f + __expf(-s.z));
    s.w = s.w / (1.f + __expf(-s.w));
    const size_t off = (size_t)tok * DI_ + d;
    *(float4*)&xs[off] = s;
    const ushort_t h0 = f2bf(s.x), h1 = f2bf(s.y), h2 = f2bf(s.z), h3 = f2bf(s.w);
    *(uint2*)&xsh[off] = make_uint2(h0 | ((unsigned)h1 << 16), h2 | ((unsigned)h3 << 16));
    const ushort_t l0 = f2bf(s.x - bf2f(h0)), l1 = f2bf(s.y - bf2f(h1));
    const ushort_t l2 = f2bf(s.z - bf2f(h2)), l3 = f2bf(s.w - bf2f(h3));
    *(uint2*)&xsl[off] = make_uint2(l0 | ((unsigned)l1 << 16), l2 | ((unsigned)l3 << 16));
}

// ---------------------------------------------------------------------------
// Chunked selective scan, no cross-lane ops.
// Pass 1 (scan_partial): one thread per (b,d,chunk); 16 n-states in registers.
//   Writes per-chunk decay product P[n] and chunk-local end state Hb[n].
// Pass 2 (scan_fix): one thread per (b,d,n); combines chunks sequentially,
//   writes each chunk's true start state Hs.
// Pass 3 (scan_final): like pass 1 but seeded with Hs; computes
//   y = (C.h + D*x) * silu(z), emits y hi/lo bf16 planes.
// Buffer layout for P/Hb/Hs: idx = ((b*NCH+c)*16+n)*DI + d  (d coalesced).
// ---------------------------------------------------------------------------
__global__ __launch_bounds__(256)
void scan_partial(const float* __restrict__ dt, const float* __restrict__ xs,
                  const float* __restrict__ xdbl, const float* __restrict__ A_log,
                  float* __restrict__ Pb, float* __restrict__ Hb)
{
    const int g  = blockIdx.x * 256 + threadIdx.x;   // (b*NCH+c)*DI + d
    const int d  = g & (DI_ - 1);
    const int bc = g >> 11;                          // b*NCH + c
    const int tok0 = (bc >> 4) * L_ + (bc & (NCH_ - 1)) * CHL_;

    float a[DS_], h[DS_], P[DS_];
    #pragma unroll
    for (int n = 0; n < DS_; n++) {
        a[n] = -expf(A_log[d * DS_ + n]);
        h[n] = 0.f; P[n] = 1.f;
    }

    #pragma unroll 1
    for (int l = 0; l < CHL_; l++) {
        const size_t tok = tok0 + l;
        const float dtv = dt[tok * DI_ + d];
        const float xv  = xs[tok * DI_ + d];
        const float dbx = dtv * xv;
        const float* bp = xdbl + tok * 96 + 64;
        const float4 B0 = *(const float4*)(bp + 0);
        const float4 B1 = *(const float4*)(bp + 4);
        const float4 B2 = *(const float4*)(bp + 8);
        const float4 B3 = *(const float4*)(bp + 12);
        const float Bv[DS_] = {B0.x,B0.y,B0.z,B0.w, B1.x,B1.y,B1.z,B1.w,
                               B2.x,B2.y,B2.z,B2.w, B3.x,B3.y,B3.z,B3.w};
        #pragma unroll
        for (int n = 0; n < DS_; n++) {
            const float dA = __expf(dtv * a[n]);
            h[n] = fmaf(dA, h[n], dbx * Bv[n]);
            P[n] *= dA;
        }
    }
    #pragma unroll
    for (int n = 0; n < DS_; n++) {
        const size_t idx = ((size_t)bc * DS_ + n) * DI_ + d;
        Pb[idx] = P[n];
        Hb[idx] = h[n];
    }
}

__global__ __launch_bounds__(256)
void scan_fix(const float* __restrict__ Pb, const float* __restrict__ Hb,
              float* __restrict__ Hs)
{
    const int g  = blockIdx.x * 256 + threadIdx.x;   // (b*16+n)*DI + d
    const int d  = g & (DI_ - 1);
    const int bn = g >> 11;
    const int b  = bn >> 4;
    const int n  = bn & (DS_ - 1);
    float hs = 0.f;
    #pragma unroll 1
    for (int c = 0; c < NCH_; c++) {
        const size_t idx = ((size_t)(b * NCH_ + c) * DS_ + n) * DI_ + d;
        Hs[idx] = hs;
        hs = fmaf(Pb[idx], hs, Hb[idx]);
    }
}

__global__ __launch_bounds__(256)
void scan_final(const float* __restrict__ dt, const float* __restrict__ xs,
                const float* __restrict__ xdbl, const float* __restrict__ xz,
                const float* __restrict__ Hs, const float* __restrict__ A_log,
                const float* __restrict__ Dp,
                ushort_t* __restrict__ yh, ushort_t* __restrict__ yl)
{
    const int g  = blockIdx.x * 256 + threadIdx.x;   // (b*NCH+c)*DI + d
    const int d  = g & (DI_ - 1);
    const int bc = g >> 11;
    const int tok0 = (bc >> 4) * L_ + (bc & (NCH_ - 1)) * CHL_;
    const float Dd = Dp[d];

    float a[DS_], h[DS_];
    #pragma unroll
    for (int n = 0; n < DS_; n++) {
        a[n] = -expf(A_log[d * DS_ + n]);
        h[n] = Hs[((size_t)bc * DS_ + n) * DI_ + d];
    }

    #pragma unroll 1
    for (int l = 0; l < CHL_; l++) {
        const size_t tok = tok0 + l;
        const float dtv = dt[tok * DI_ + d];
        const float xv  = xs[tok * DI_ + d];
        const float zv  = xz[tok * (2 * DI_) + DI_ + d];
        const float dbx = dtv * xv;
        const float* bp = xdbl + tok * 96 + 64;
        const float4 B0 = *(const float4*)(bp + 0);
        const float4 B1 = *(const float4*)(bp + 4);
        const float4 B2 = *(const float4*)(bp + 8);
        const float4 B3 = *(const float4*)(bp + 12);
        const float4 C0 = *(const float4*)(bp + 16);
        const float4 C1 = *(const float4*)(bp + 20);
        const float4 C2 = *(const float4*)(bp + 24);
        const float4 C3 = *(const float4*)(bp + 28);
        const float Bv[DS_] = {B0.x,B0.y,B0.z,B0.w, B1.x,B1.y,B1.z,B1.w,
                               B2.x,B2.y,B2.z,B2.w, B3.x,B3.y,B3.z,B3.w};
        const float Cv[DS_] = {C0.x,C0.y,C0.z,C0.w, C1.x,C1.y,C1.z,C1.w,
                               C2.x,C2.y,C2.z,C2.w, C3.x,C3.y,C3.z,C3.w};
        float acc = 0.f;
        #pragma unroll
        for (int n = 0; n < DS_; n++) {
            const float dA = __expf(dtv * a[n]);
            h[n] = fmaf(dA, h[n], dbx * Bv[n]);
            acc  = fmaf(h[n], Cv[n], acc);
        }
        const float sz = zv / (1.f + __expf(-zv));
        const float yv = fmaf(Dd, xv, acc) * sz;
        const size_t idx = tok * DI_ + d;
        const ushort_t hh = f2bf(yv);
        yh[idx] = hh;
        yl[idx] = f2bf(yv - bf2f(hh));
    }
}

// ---------------------------------------------------------------------------
// out = LN(a + r) * w + b ; optional hi/lo bf16 planes. One block per token.
// ---------------------------------------------------------------------------
__global__ __launch_bounds__(256)
void ln_kernel(const float* __restrict__ a, const float* __restrict__ r,
               const float* __restrict__ w, const float* __restrict__ b,
               float* __restrict__ out,
               ushort_t* __restrict__ oh, ushort_t* __restrict__ ol)
{
    const int tok = blockIdx.x;
    const int tid = threadIdx.x;
    const size_t off = (size_t)tok * DM_ + tid * 4;
    const float4 va = *(const float4*)&a[off];
    const float4 vr = *(const float4*)&r[off];
    const float xv[4] = {va.x + vr.x, va.y + vr.y, va.z + vr.z, va.w + vr.w};

    float s  = xv[0] + xv[1] + xv[2] + xv[3];
    float sq = xv[0]*xv[0] + xv[1]*xv[1] + xv[2]*xv[2] + xv[3]*xv[3];
    #pragma unroll
    for (int o = 32; o > 0; o >>= 1) {
        s  += __shfl_xor(s,  o, 64);
        sq += __shfl_xor(sq, o, 64);
    }
    __shared__ float ss[4], sqs[4];
    const int wid = tid >> 6;
    if ((tid & 63) == 0) { ss[wid] = s; sqs[wid] = sq; }
    __syncthreads();
    s  = ss[0] + ss[1] + ss[2] + ss[3];
    sq = sqs[0] + sqs[1] + sqs[2] + sqs[3];

    const float mean = s * (1.f / DM_);
    const float var  = sq * (1.f / DM_) - mean * mean;
    const float rs   = rsqrtf(var + 1e-12f);

    const float4 vw = *(const float4*)&w[tid * 4];
    const float4 vb = *(const float4*)&b[tid * 4];
    const float o0 = (xv[0] - mean) * rs * vw.x + vb.x;
    const float o1 = (xv[1] - mean) * rs * vw.y + vb.y;
    const float o2 = (xv[2] - mean) * rs * vw.z + vb.z;
    const float o3 = (xv[3] - mean) * rs * vw.w + vb.w;
    *(float4*)&out[off] = make_float4(o0, o1, o2, o3);
    if (oh) {
        const ushort_t h0 = f2bf(o0), h1 = f2bf(o1), h2 = f2bf(o2), h3 = f2bf(o3);
        *(uint2*)&oh[off] = make_uint2(h0 | ((unsigned)h1 << 16), h2 | ((unsigned)h3 << 16));
        const ushort_t l0 = f2bf(o0 - bf2f(h0)), l1 = f2bf(o1 - bf2f(h1));
        const ushort_t l2 = f2bf(o2 - bf2f(h2)), l3 = f2bf(o3 - bf2f(h3));
        *(uint2*)&ol[off] = make_uint2(l0 | ((unsigned)l1 << 16), l2 | ((unsigned)l3 << 16));
    }
}

// ---------------------------------------------------------------------------
extern "C" void kernel_launch(void* const* d_in, const int* in_sizes, int n_in,
                              void* d_out, int out_size, void* d_ws, size_t ws_size,
                              hipStream_t stream)
{
    const float* x        = (const float*)d_in[0];
    const float* in_w     = (const float*)d_in[1];
    const float* conv_w   = (const float*)d_in[2];
    const float* conv_b   = (const float*)d_in[3];
    const float* xproj_w  = (const float*)d_in[4];
    const float* dtproj_w = (const float*)d_in[5];
    const float* dtproj_b = (const float*)d_in[6];
    const float* A_log    = (const float*)d_in[7];
    const float* Dp       = (const float*)d_in[8];
    const float* outw     = (const float*)d_in[9];
    const float* ln1w     = (const float*)d_in[10];
    const float* ln1b     = (const float*)d_in[11];
    const float* fw1      = (const float*)d_in[12];
    const float* fb1      = (const float*)d_in[13];
    const float* fw2      = (const float*)d_in[14];
    const float* fb2      = (const float*)d_in[15];
    const float* ln2w     = (const float*)d_in[16];
    const float* ln2b     = (const float*)d_in[17];
    float* out = (float*)d_out;

    const int M = B_ * L_;   // 2048
    // ---- workspace carve (floats). total ~171 MB ----
    float* p = (float*)d_ws;
    float* xz     = p; p += (size_t)M * 4096;          // fp32
    float* xsact  = p; p += (size_t)M * 2048;          // fp32
    float* xsact_h= p; p += (size_t)M * 2048 / 2;      // bf16 plane (also hres planes later)
    float* xsact_l= p; p += (size_t)M * 2048 / 2;
    float* xdbl   = p; p += (size_t)M * 96;
    float* xdbl_h = p; p += (size_t)M * 96 / 2;
    float* xdbl_l = p; p += (size_t)M * 96 / 2;
    float* dtb    = p; p += (size_t)M * 2048;
    float* y_h    = p; p += (size_t)M * 2048 / 2;      // also f1 planes later
    float* y_l    = p; p += (size_t)M * 2048 / 2;
    float* mo     = p; p += (size_t)M * 1024;
    float* hres   = p; p += (size_t)M * 1024;
    float* x_h    = p; p += (size_t)M * 1024 / 2;      // dead after in_proj -> Hs
    float* x_l    = p; p += (size_t)M * 1024 / 2;      //   (x_h+x_l contiguous)
    float* inw_h  = p; p += (size_t)4096 * 1024 / 2;   // dead after in_proj -> Pb
    float* inw_l  = p; p += (size_t)4096 * 1024 / 2;   // dead after in_proj -> Hb
    float* xpw_h  = p; p += (size_t)128 * 2048 / 2;    // 96 rows used, padded to 128
    float* xpw_l  = p; p += (size_t)128 * 2048 / 2;
    float* dtw_h  = p; p += (size_t)2048 * 64 / 2;
    float* dtw_l  = p; p += (size_t)2048 * 64 / 2;
    float* ow_h   = p; p += (size_t)1024 * 2048 / 2;
    float* ow_l   = p; p += (size_t)1024 * 2048 / 2;
    float* f1w_h  = p; p += (size_t)2048 * 1024 / 2;
    float* f1w_l  = p; p += (size_t)2048 * 1024 / 2;
    float* f2w_h  = p; p += (size_t)1024 * 2048 / 2;
    float* f2w_l  = p; p += (size_t)1024 * 2048 / 2;

    ushort_t* h_h  = (ushort_t*)xsact_h;   // overlay: xsact planes dead after x_proj
    ushort_t* h_l  = (ushort_t*)xsact_l;
    ushort_t* f1_h = (ushort_t*)y_h;       // overlay: y planes dead after out_proj
    ushort_t* f1_l = (ushort_t*)y_l;
    // scan chunk buffers overlay regions dead after in_proj:
    //   Pb -> inw_h (2.097M floats), Hb -> inw_l, Hs -> x_h..x_l (2.097M floats)
    float* Pb = inw_h;     // B*NCH*DS*DI = 4*16*16*2048 = 2.097M floats each
    float* Hb = inw_l;
    float* Hs = x_h;

    const dim3 blk(256);

    // ---- single batched conversion launch (7 segments) ----
    CvtArgs ca;
    const float* srcs[NSEG] = {x, in_w, xproj_w, dtproj_w, outw, fw1, fw2};
    ushort_t* his[NSEG] = {(ushort_t*)x_h, (ushort_t*)inw_h, (ushort_t*)xpw_h,
                           (ushort_t*)dtw_h, (ushort_t*)ow_h, (ushort_t*)f1w_h,
                           (ushort_t*)f2w_h};
    ushort_t* los[NSEG] = {(ushort_t*)x_l, (ushort_t*)inw_l, (ushort_t*)xpw_l,
                           (ushort_t*)dtw_l, (ushort_t*)ow_l, (ushort_t*)f1w_l,
                           (ushort_t*)f2w_l};
    const int n4s[NSEG] = {M * 1024 / 4, 4096 * 1024 / 4, 96 * 2048 / 4,
                           2048 * 64 / 4, 1024 * 2048 / 4, 2048 * 1024 / 4,
                           1024 * 2048 / 4};
    int acc4 = 0;
    for (int s = 0; s < NSEG; s++) {
        ca.src[s] = srcs[s]; ca.hi[s] = his[s]; ca.lo[s] = los[s];
        ca.start4[s] = acc4; acc4 += n4s[s];
    }
    ca.total4 = acc4;
    cvt_multi<<<dim3((acc4 + 255) / 256), blk, 0, stream>>>(ca);

    // 1. in_proj: xz = x @ in_w^T   (2048 x 4096 x 1024)
    gemm_mfma<0><<<dim3(32, 16), blk, 0, stream>>>(
        (ushort_t*)x_h, (ushort_t*)x_l, 1024,
        (ushort_t*)inw_h, (ushort_t*)inw_l, 1024,
        nullptr, xz, nullptr, nullptr, 4096, 4096, 1024);
    // 2. conv + silu (emits fp32 + planes)
    conv_silu_kernel<<<dim3(M * DI_ / 4 / 256), blk, 0, stream>>>(
        xz, conv_w, conv_b, xsact, (ushort_t*)xsact_h, (ushort_t*)xsact_l);
    // 3. x_proj: xdbl (2048 x 96 x 2048), fp32 + planes
    gemm_mfma<0><<<dim3(1, 16), blk, 0, stream>>>(
        (ushort_t*)xsact_h, (ushort_t*)xsact_l, 2048,
        (ushort_t*)xpw_h, (ushort_t*)xpw_l, 2048,
        nullptr, xdbl, (ushort_t*)xdbl_h, (ushort_t*)xdbl_l, 96, 96, 2048);
    // 4. dt = softplus(dt_r @ dt_w^T + b)  (2048 x 2048 x 64)
    gemm_mfma<1><<<dim3(16, 16), blk, 0, stream>>>(
        (ushort_t*)xdbl_h, (ushort_t*)xdbl_l, 96,
        (ushort_t*)dtw_h, (ushort_t*)dtw_l, 64,
        dtproj_b, dtb, nullptr, nullptr, 2048, 2048, 64);
    // 5. chunked scan: partial -> fix -> final (emits y planes)
    scan_partial<<<dim3(B_ * NCH_ * DI_ / 256), blk, 0, stream>>>(
        dtb, xsact, xdbl, A_log, Pb, Hb);
    scan_fix<<<dim3(B_ * DS_ * DI_ / 256), blk, 0, stream>>>(Pb, Hb, Hs);
    scan_final<<<dim3(B_ * NCH_ * DI_ / 256), blk, 0, stream>>>(
        dtb, xsact, xdbl, xz, Hs, A_log, Dp, (ushort_t*)y_h, (ushort_t*)y_l);
    // 6. out_proj: mo (2048 x 1024 x 2048)
    gemm_mfma<0><<<dim3(8, 16), blk, 0, stream>>>(
        (ushort_t*)y_h, (ushort_t*)y_l, 2048,
        (ushort_t*)ow_h, (ushort_t*)ow_l, 2048,
        nullptr, mo, nullptr, nullptr, 1024, 1024, 2048);
    // 7. hres = LN1(mo + x)  (+ planes)
    ln_kernel<<<dim3(M), blk, 0, stream>>>(mo, x, ln1w, ln1b, hres, h_h, h_l);
    // 8. ffn1 + leakyrelu -> f1 planes only  (2048 x 2048 x 1024)
    gemm_mfma<2><<<dim3(16, 16), blk, 0, stream>>>(
        h_h, h_l, 1024,
        (ushort_t*)f1w_h, (ushort_t*)f1w_l, 1024,
        fb1, nullptr, f1_h, f1_l, 2048, 2048, 1024);
    // 9. ffn2 + bias -> mo  (2048 x 1024 x 2048)
    gemm_mfma<3><<<dim3(8, 16), blk, 0, stream>>>(
        f1_h, f1_l, 2048,
        (ushort_t*)f2w_h, (ushort_t*)f2w_l, 2048,
        fb2, mo, nullptr, nullptr, 1024, 1024, 2048);
    // 10. out = LN2(mo + hres)
    ln_kernel<<<dim3(M), blk, 0, stream>>>(mo, hres, ln2w, ln2b, out, nullptr, nullptr);
}

// Round 6
// 685.887 us; speedup vs baseline: 1.6087x; 1.2888x over previous
//
#include <hip/hip_runtime.h>
#include <math.h>

#define B_   4
#define L_   512
#define DM_  1024
#define DS_  16
#define DC_  4
#define DI_  2048
#define DTR_ 64
#define NCH_ 16
#define CHL_ 32   // L_ / NCH_

typedef unsigned short ushort_t;
typedef __attribute__((ext_vector_type(8))) short short8v;
typedef __attribute__((ext_vector_type(4))) float f32x4;

__device__ __forceinline__ ushort_t f2bf(float f) {
    unsigned u = __float_as_uint(f);
    return (ushort_t)((u + 0x7fffu + ((u >> 16) & 1u)) >> 16);
}
__device__ __forceinline__ float bf2f(ushort_t h) {
    return __uint_as_float((unsigned)h << 16);
}

// ---------------------------------------------------------------------------
// Batched fp32 -> (hi, lo) bf16 plane conversion: 7 segments in one launch.
// ---------------------------------------------------------------------------
#define NSEG 7
struct CvtArgs {
    const float* src[NSEG];
    ushort_t*    hi[NSEG];
    ushort_t*    lo[NSEG];
    int start4[NSEG];
    int total4;
};

__global__ __launch_bounds__(256)
void cvt_multi(CvtArgs a)
{
    const int i = blockIdx.x * 256 + threadIdx.x;
    if (i >= a.total4) return;
    int s = 0;
    #pragma unroll
    for (int k = 1; k < NSEG; k++) s += (i >= a.start4[k]) ? 1 : 0;
    const int j = i - a.start4[s];

    const float4 v = ((const float4*)a.src[s])[j];
    const ushort_t h0 = f2bf(v.x), h1 = f2bf(v.y), h2 = f2bf(v.z), h3 = f2bf(v.w);
    ((uint2*)a.hi[s])[j] = make_uint2(h0 | ((unsigned)h1 << 16), h2 | ((unsigned)h3 << 16));
    const ushort_t l0 = f2bf(v.x - bf2f(h0)), l1 = f2bf(v.y - bf2f(h1));
    const ushort_t l2 = f2bf(v.z - bf2f(h2)), l3 = f2bf(v.w - bf2f(h3));
    ((uint2*)a.lo[s])[j] = make_uint2(l0 | ((unsigned)l1 << 16), l2 | ((unsigned)l3 << 16));
}

// ---------------------------------------------------------------------------
// Split-bf16 MFMA GEMM, 2-phase pipelined (double LDS buffer, counted vmcnt,
// raw s_barrier). C[M,N] = A[M,K] @ W[N,K]^T. 4 waves in 2x2, wave tile
// (BM/2)x(BN/2). KS>1 => split-K: blockIdx.z owns K/KS chunk, writes fp32
// partial at C + z*pstride (no epilogue; reduce kernel finishes).
// EPI: 0 none, 1 bias+softplus, 2 bias+leakyrelu, 3 bias.
// ---------------------------------------------------------------------------
template<int EPI, int BM, int BN, int KS>
__global__ __launch_bounds__(256, 2)
void gemm_mfma(const ushort_t* __restrict__ Ahi, const ushort_t* __restrict__ Alo, int lda,
               const ushort_t* __restrict__ Whi, const ushort_t* __restrict__ Wlo, int ldw,
               const float* __restrict__ bias,
               float* __restrict__ C, ushort_t* __restrict__ Chi, ushort_t* __restrict__ Clo,
               int ldc, size_t pstride, int N, int K)
{
    constexpr int WM  = BM / 32;        // 16x16 frags per wave, m-dir
    constexpr int WN  = BN / 32;
    constexpr int PLA = BM * 32;        // ushorts per A plane (one buffer)
    constexpr int PLB = BN * 32;
    constexpr int BUF = 2 * PLA + 2 * PLB;
    __shared__ ushort_t lds[2 * BUF];

    const int t    = threadIdx.x;
    const int lane = t & 63;
    const int wv   = t >> 6;
    const int wm   = (wv >> 1) * (BM / 2);
    const int wn   = (wv & 1) * (BN / 2);
    const int m0   = blockIdx.y * BM;
    const int n0   = blockIdx.x * BN;
    const int fr   = lane & 15;
    const int fc   = lane >> 4;

    // staging: wave wv owns plane wv (0=Ah 1=Al 2=Wh 3=Wl)
    const int R     = (wv < 2) ? BM : BN;            // rows in my plane
    const int pb    = (wv < 2) ? wv * PLA : 2 * PLA + (wv - 2) * PLB;
    const ushort_t* gbase = (wv == 0) ? Ahi : (wv == 1) ? Alo : (wv == 2) ? Whi : Wlo;
    const int grow0 = ((wv < 2) ? m0 : n0) + lane;
    const int gld   = (wv < 2) ? lda : ldw;
    const int NL    = R >> 6;                        // 64-row groups (1 or 2)

    auto STAGE = [&](int bufi, int k0) {
        for (int c = 0; c < 4; c++)
            for (int h = 0; h < NL; h++) {
                const ushort_t* g = gbase + (size_t)(grow0 + h * 64) * gld + (k0 + c * 8);
                ushort_t* l = &lds[bufi * BUF + pb + (c * R + h * 64) * 8];
                __builtin_amdgcn_global_load_lds(
                    (const __attribute__((address_space(1))) void*)g,
                    (__attribute__((address_space(3))) void*)l, 16, 0, 0);
            }
    };

    f32x4 acc[WM][WN];
    #pragma unroll
    for (int i = 0; i < WM; i++)
        #pragma unroll
        for (int j = 0; j < WN; j++)
            acc[i][j] = (f32x4){0.f, 0.f, 0.f, 0.f};

    const int kbeg = blockIdx.z * (K / KS);
    const int nt   = (K / KS) / 32;

    STAGE(0, kbeg);
    int cur = 0;
    for (int tt = 0; tt < nt; ++tt) {
        if (tt + 1 < nt) {
            STAGE(cur ^ 1, kbeg + (tt + 1) * 32);
            // wait for MY tile-tt loads (tile-tt+1's stay in flight)
            if (R == 128) asm volatile("s_waitcnt vmcnt(8)" ::: "memory");
            else          asm volatile("s_waitcnt vmcnt(4)" ::: "memory");
        } else {
            asm volatile("s_waitcnt vmcnt(0)" ::: "memory");
        }
        __builtin_amdgcn_s_barrier();          // everyone's tile-tt data in LDS
        asm volatile("" ::: "memory");

        const int bb = cur * BUF;
        short8v ah[WM], al[WM];
        #pragma unroll
        for (int i = 0; i < WM; i++) {
            const int ro = fc * BM + wm + i * 16 + fr;
            ah[i] = *(const short8v*)&lds[bb + ro * 8];
            al[i] = *(const short8v*)&lds[bb + PLA + ro * 8];
        }
        #pragma unroll
        for (int j = 0; j < WN; j++) {
            const int ro = fc * BN + wn + j * 16 + fr;
            const short8v bh = *(const short8v*)&lds[bb + 2 * PLA + ro * 8];
            const short8v bl = *(const short8v*)&lds[bb + 2 * PLA + PLB + ro * 8];
            #pragma unroll
            for (int i = 0; i < WM; i++) {
                acc[i][j] = __builtin_amdgcn_mfma_f32_16x16x32_bf16(al[i], bh, acc[i][j], 0, 0, 0);
                acc[i][j] = __builtin_amdgcn_mfma_f32_16x16x32_bf16(ah[i], bl, acc[i][j], 0, 0, 0);
                acc[i][j] = __builtin_amdgcn_mfma_f32_16x16x32_bf16(ah[i], bh, acc[i][j], 0, 0, 0);
            }
        }
        if (tt + 1 < nt) {
            __builtin_amdgcn_s_barrier();      // all reads of buf[cur] done
            asm volatile("" ::: "memory");
        }
        cur ^= 1;
    }

    // ---- epilogue: D row = (lane>>4)*4 + reg, col = lane&15 ----
    if (KS > 1) {
        float* Cp = C + (size_t)blockIdx.z * pstride;
        #pragma unroll
        for (int j = 0; j < WN; j++) {
            const int c = n0 + wn + j * 16 + fr;
            if (c < N) {
                #pragma unroll
                for (int i = 0; i < WM; i++) {
                    const int r = m0 + wm + i * 16 + fc * 4;
                    #pragma unroll
                    for (int q = 0; q < 4; q++)
                        Cp[(size_t)(r + q) * ldc + c] = acc[i][j][q];
                }
            }
        }
        return;
    }
    #pragma unroll
    for (int j = 0; j < WN; j++) {
        const int c = n0 + wn + j * 16 + fr;
        float bj = 0.f;
        if (EPI != 0) bj = bias[c];            // EPI!=0 only with tile-aligned N
        if (c < N) {
            #pragma unroll
            for (int i = 0; i < WM; i++) {
                const int r = m0 + wm + i * 16 + fc * 4;
                #pragma unroll
                for (int q = 0; q < 4; q++) {
                    float v = acc[i][j][q] + bj;
                    if (EPI == 1) v = fmaxf(v, 0.f) + log1pf(expf(-fabsf(v)));
                    else if (EPI == 2) v = (v >= 0.f) ? v : 0.01f * v;
                    const size_t idx = (size_t)(r + q) * ldc + c;
                    if (C) C[idx] = v;
                    if (Chi) {
                        const ushort_t h = f2bf(v);
                        Chi[idx] = h;
                        Clo[idx] = f2bf(v - bf2f(h));
                    }
                }
            }
        }
    }
}

// ---------------------------------------------------------------------------
// Split-K reduce: sum KS fp32 partials, optional bias (EPI==3), write fp32
// and/or hi/lo planes.
// ---------------------------------------------------------------------------
template<int EPI, int KS>
__global__ __launch_bounds__(256)
void reduce_k(const float* __restrict__ part, size_t mn4, int ldc,
              const float* __restrict__ bias,
              float* __restrict__ C, ushort_t* __restrict__ Chi, ushort_t* __restrict__ Clo)
{
    const size_t i = (size_t)blockIdx.x * 256 + threadIdx.x;
    if (i >= mn4) return;
    float4 s = ((const float4*)part)[i];
    #pragma unroll
    for (int z = 1; z < KS; z++) {
        const float4 v = ((const float4*)(part + (size_t)z * mn4 * 4))[i];
        s.x += v.x; s.y += v.y; s.z += v.z; s.w += v.w;
    }
    if (EPI == 3) {
        const int col = (int)((i * 4) % (size_t)ldc);
        const float4 b = *(const float4*)&bias[col];
        s.x += b.x; s.y += b.y; s.z += b.z; s.w += b.w;
    }
    if (C) ((float4*)C)[i] = s;
    if (Chi) {
        const ushort_t h0 = f2bf(s.x), h1 = f2bf(s.y), h2 = f2bf(s.z), h3 = f2bf(s.w);
        ((uint2*)Chi)[i] = make_uint2(h0 | ((unsigned)h1 << 16), h2 | ((unsigned)h3 << 16));
        const ushort_t l0 = f2bf(s.x - bf2f(h0)), l1 = f2bf(s.y - bf2f(h1));
        const ushort_t l2 = f2bf(s.z - bf2f(h2)), l3 = f2bf(s.w - bf2f(h3));
        ((uint2*)Clo)[i] = make_uint2(l0 | ((unsigned)l1 << 16), l2 | ((unsigned)l3 << 16));
    }
}

// ---------------------------------------------------------------------------
// Depthwise causal conv (DC=4) + bias + SiLU; emits fp32 + hi/lo bf16.
// ---------------------------------------------------------------------------
__global__ __launch_bounds__(256)
void conv_silu_kernel(const float* __restrict__ xz,
                      const float* __restrict__ cw,
                      const float* __restrict__ cb,
                      float* __restrict__ xs,
                      ushort_t* __restrict__ xsh, ushort_t* __restrict__ xsl)
{
    const int g   = blockIdx.x * 256 + threadIdx.x;   // quad id
    const int d   = (g & (DI_ / 4 - 1)) * 4;
    const int tok = g >> 9;
    const int l   = tok & (L_ - 1);
    const int t0  = tok - l;
    const float4 w0 = *(const float4*)&cw[(d + 0) * 4];
    const float4 w1 = *(const float4*)&cw[(d + 1) * 4];
    const float4 w2 = *(const float4*)&cw[(d + 2) * 4];
    const float4 w3 = *(const float4*)&cw[(d + 3) * 4];
    float4 s = *(const float4*)&cb[d];
    if (l >= 3) { const float4 v = *(const float4*)&xz[(size_t)(t0 + l - 3) * (2 * DI_) + d];
        s.x += w0.x * v.x; s.y += w1.x * v.y; s.z += w2.x * v.z; s.w += w3.x * v.w; }
    if (l >= 2) { const float4 v = *(const float4*)&xz[(size_t)(t0 + l - 2) * (2 * DI_) + d];
        s.x += w0.y * v.x; s.y += w1.y * v.y; s.z += w2.y * v.z; s.w += w3.y * v.w; }
    if (l >= 1) { const float4 v = *(const float4*)&xz[(size_t)(t0 + l - 1) * (2 * DI_) + d];
        s.x += w0.z * v.x; s.y += w1.z * v.y; s.z += w2.z * v.z; s.w += w3.z * v.w; }
    {           const float4 v = *(const float4*)&xz[(size_t)(t0 + l) * (2 * DI_) + d];
        s.x += w0.w * v.x; s.y += w1.w * v.y; s.z += w2.w * v.z; s.w += w3.w * v.w; }
    s.x = s.x / (1.f + __expf(-s.x));
    s.y = s.y / (1.f + __expf(-s.y));
    s.z = s.z / (1.f + __expf(-s.z));
    s.w = s.w / (1.f + __expf(-s.w));
    const size_t off = (size_t)tok * DI_ + d;
    *(float4*)&xs[off] = s;
    const ushort_t h0 = f2bf(s.x), h1 = f2bf(s.y), h2 = f2bf(s.z), h3 = f2bf(s.w);
    *(uint2*)&xsh[off] = make_uint2(h0 | ((unsigned)h1 << 16), h2 | ((unsigned)h3 << 16));
    const ushort_t l0 = f2bf(s.x - bf2f(h0)), l1 = f2bf(s.y - bf2f(h1));
    const ushort_t l2 = f2bf(s.z - bf2f(h2)), l3 = f2bf(s.w - bf2f(h3));
    *(uint2*)&xsl[off] = make_uint2(l0 | ((unsigned)l1 << 16), l2 | ((unsigned)l3 << 16));
}

// ---------------------------------------------------------------------------
// Chunked selective scan (no cross-lane ops): partial -> fix -> final.
// ---------------------------------------------------------------------------
__global__ __launch_bounds__(256)
void scan_partial(const float* __restrict__ dt, const float* __restrict__ xs,
                  const float* __restrict__ xdbl, const float* __restrict__ A_log,
                  float* __restrict__ Pb, float* __restrict__ Hb)
{
    const int g  = blockIdx.x * 256 + threadIdx.x;   // (b*NCH+c)*DI + d
    const int d  = g & (DI_ - 1);
    const int bc = g >> 11;
    const int tok0 = (bc >> 4) * L_ + (bc & (NCH_ - 1)) * CHL_;

    float a[DS_], h[DS_], P[DS_];
    #pragma unroll
    for (int n = 0; n < DS_; n++) {
        a[n] = -expf(A_log[d * DS_ + n]);
        h[n] = 0.f; P[n] = 1.f;
    }

    #pragma unroll 1
    for (int l = 0; l < CHL_; l++) {
        const size_t tok = tok0 + l;
        const float dtv = dt[tok * DI_ + d];
        const float xv  = xs[tok * DI_ + d];
        const float dbx = dtv * xv;
        const float* bp = xdbl + tok * 96 + 64;
        const float4 B0 = *(const float4*)(bp + 0);
        const float4 B1 = *(const float4*)(bp + 4);
        const float4 B2 = *(const float4*)(bp + 8);
        const float4 B3 = *(const float4*)(bp + 12);
        const float Bv[DS_] = {B0.x,B0.y,B0.z,B0.w, B1.x,B1.y,B1.z,B1.w,
                               B2.x,B2.y,B2.z,B2.w, B3.x,B3.y,B3.z,B3.w};
        #pragma unroll
        for (int n = 0; n < DS_; n++) {
            const float dA = __expf(dtv * a[n]);
            h[n] = fmaf(dA, h[n], dbx * Bv[n]);
            P[n] *= dA;
        }
    }
    #pragma unroll
    for (int n = 0; n < DS_; n++) {
        const size_t idx = ((size_t)bc * DS_ + n) * DI_ + d;
        Pb[idx] = P[n];
        Hb[idx] = h[n];
    }
}

__global__ __launch_bounds__(256)
void scan_fix(const float* __restrict__ Pb, const float* __restrict__ Hb,
              float* __restrict__ Hs)
{
    const int g  = blockIdx.x * 256 + threadIdx.x;   // (b*16+n)*DI + d
    const int d  = g & (DI_ - 1);
    const int bn = g >> 11;
    const int b  = bn >> 4;
    const int n  = bn & (DS_ - 1);
    float hs = 0.f;
    #pragma unroll 1
    for (int c = 0; c < NCH_; c++) {
        const size_t idx = ((size_t)(b * NCH_ + c) * DS_ + n) * DI_ + d;
        Hs[idx] = hs;
        hs = fmaf(Pb[idx], hs, Hb[idx]);
    }
}

__global__ __launch_bounds__(256)
void scan_final(const float* __restrict__ dt, const float* __restrict__ xs,
                const float* __restrict__ xdbl, const float* __restrict__ xz,
                const float* __restrict__ Hs, const float* __restrict__ A_log,
                const float* __restrict__ Dp,
                ushort_t* __restrict__ yh, ushort_t* __restrict__ yl)
{
    const int g  = blockIdx.x * 256 + threadIdx.x;   // (b*NCH+c)*DI + d
    const int d  = g & (DI_ - 1);
    const int bc = g >> 11;
    const int tok0 = (bc >> 4) * L_ + (bc & (NCH_ - 1)) * CHL_;
    const float Dd = Dp[d];

    float a[DS_], h[DS_];
    #pragma unroll
    for (int n = 0; n < DS_; n++) {
        a[n] = -expf(A_log[d * DS_ + n]);
        h[n] = Hs[((size_t)bc * DS_ + n) * DI_ + d];
    }

    #pragma unroll 1
    for (int l = 0; l < CHL_; l++) {
        const size_t tok = tok0 + l;
        const float dtv = dt[tok * DI_ + d];
        const float xv  = xs[tok * DI_ + d];
        const float zv  = xz[tok * (2 * DI_) + DI_ + d];
        const float dbx = dtv * xv;
        const float* bp = xdbl + tok * 96 + 64;
        const float4 B0 = *(const float4*)(bp + 0);
        const float4 B1 = *(const float4*)(bp + 4);
        const float4 B2 = *(const float4*)(bp + 8);
        const float4 B3 = *(const float4*)(bp + 12);
        const float4 C0 = *(const float4*)(bp + 16);
        const float4 C1 = *(const float4*)(bp + 20);
        const float4 C2 = *(const float4*)(bp + 24);
        const float4 C3 = *(const float4*)(bp + 28);
        const float Bv[DS_] = {B0.x,B0.y,B0.z,B0.w, B1.x,B1.y,B1.z,B1.w,
                               B2.x,B2.y,B2.z,B2.w, B3.x,B3.y,B3.z,B3.w};
        const float Cv[DS_] = {C0.x,C0.y,C0.z,C0.w, C1.x,C1.y,C1.z,C1.w,
                               C2.x,C2.y,C2.z,C2.w, C3.x,C3.y,C3.z,C3.w};
        float acc = 0.f;
        #pragma unroll
        for (int n = 0; n < DS_; n++) {
            const float dA = __expf(dtv * a[n]);
            h[n] = fmaf(dA, h[n], dbx * Bv[n]);
            acc  = fmaf(h[n], Cv[n], acc);
        }
        const float sz = zv / (1.f + __expf(-zv));
        const float yv = fmaf(Dd, xv, acc) * sz;
        const size_t idx = tok * DI_ + d;
        const ushort_t hh = f2bf(yv);
        yh[idx] = hh;
        yl[idx] = f2bf(yv - bf2f(hh));
    }
}

// ---------------------------------------------------------------------------
// out = LN(a + r) * w + b ; optional hi/lo bf16 planes. One block per token.
// ---------------------------------------------------------------------------
__global__ __launch_bounds__(256)
void ln_kernel(const float* __restrict__ a, const float* __restrict__ r,
               const float* __restrict__ w, const float* __restrict__ b,
               float* __restrict__ out,
               ushort_t* __restrict__ oh, ushort_t* __restrict__ ol)
{
    const int tok = blockIdx.x;
    const int tid = threadIdx.x;
    const size_t off = (size_t)tok * DM_ + tid * 4;
    const float4 va = *(const float4*)&a[off];
    const float4 vr = *(const float4*)&r[off];
    const float xv[4] = {va.x + vr.x, va.y + vr.y, va.z + vr.z, va.w + vr.w};

    float s  = xv[0] + xv[1] + xv[2] + xv[3];
    float sq = xv[0]*xv[0] + xv[1]*xv[1] + xv[2]*xv[2] + xv[3]*xv[3];
    #pragma unroll
    for (int o = 32; o > 0; o >>= 1) {
        s  += __shfl_xor(s,  o, 64);
        sq += __shfl_xor(sq, o, 64);
    }
    __shared__ float ss[4], sqs[4];
    const int wid = tid >> 6;
    if ((tid & 63) == 0) { ss[wid] = s; sqs[wid] = sq; }
    __syncthreads();
    s  = ss[0] + ss[1] + ss[2] + ss[3];
    sq = sqs[0] + sqs[1] + sqs[2] + sqs[3];

    const float mean = s * (1.f / DM_);
    const float var  = sq * (1.f / DM_) - mean * mean;
    const float rs   = rsqrtf(var + 1e-12f);

    const float4 vw = *(const float4*)&w[tid * 4];
    const float4 vb = *(const float4*)&b[tid * 4];
    const float o0 = (xv[0] - mean) * rs * vw.x + vb.x;
    const float o1 = (xv[1] - mean) * rs * vw.y + vb.y;
    const float o2 = (xv[2] - mean) * rs * vw.z + vb.z;
    const float o3 = (xv[3] - mean) * rs * vw.w + vb.w;
    *(float4*)&out[off] = make_float4(o0, o1, o2, o3);
    if (oh) {
        const ushort_t h0 = f2bf(o0), h1 = f2bf(o1), h2 = f2bf(o2), h3 = f2bf(o3);
        *(uint2*)&oh[off] = make_uint2(h0 | ((unsigned)h1 << 16), h2 | ((unsigned)h3 << 16));
        const ushort_t l0 = f2bf(o0 - bf2f(h0)), l1 = f2bf(o1 - bf2f(h1));
        const ushort_t l2 = f2bf(o2 - bf2f(h2)), l3 = f2bf(o3 - bf2f(h3));
        *(uint2*)&ol[off] = make_uint2(l0 | ((unsigned)l1 << 16), l2 | ((unsigned)l3 << 16));
    }
}

// ---------------------------------------------------------------------------
extern "C" void kernel_launch(void* const* d_in, const int* in_sizes, int n_in,
                              void* d_out, int out_size, void* d_ws, size_t ws_size,
                              hipStream_t stream)
{
    const float* x        = (const float*)d_in[0];
    const float* in_w     = (const float*)d_in[1];
    const float* conv_w   = (const float*)d_in[2];
    const float* conv_b   = (const float*)d_in[3];
    const float* xproj_w  = (const float*)d_in[4];
    const float* dtproj_w = (const float*)d_in[5];
    const float* dtproj_b = (const float*)d_in[6];
    const float* A_log    = (const float*)d_in[7];
    const float* Dp       = (const float*)d_in[8];
    const float* outw     = (const float*)d_in[9];
    const float* ln1w     = (const float*)d_in[10];
    const float* ln1b     = (const float*)d_in[11];
    const float* fw1      = (const float*)d_in[12];
    const float* fb1      = (const float*)d_in[13];
    const float* fw2      = (const float*)d_in[14];
    const float* fb2      = (const float*)d_in[15];
    const float* ln2w     = (const float*)d_in[16];
    const float* ln2b     = (const float*)d_in[17];
    float* out = (float*)d_out;

    const int M = B_ * L_;   // 2048
    // ---- workspace carve (floats). total ~171 MB ----
    float* p = (float*)d_ws;
    float* xz     = p; p += (size_t)M * 4096;
    float* xsact  = p; p += (size_t)M * 2048;
    float* xsact_h= p; p += (size_t)M * 2048 / 2;
    float* xsact_l= p; p += (size_t)M * 2048 / 2;
    float* xdbl   = p; p += (size_t)M * 96;
    float* xdbl_h = p; p += (size_t)M * 96 / 2;
    float* xdbl_l = p; p += (size_t)M * 96 / 2;
    float* dtb    = p; p += (size_t)M * 2048;          // also x_proj split-K partials
    float* y_h    = p; p += (size_t)M * 2048 / 2;
    float* y_l    = p; p += (size_t)M * 2048 / 2;
    float* mo     = p; p += (size_t)M * 1024;
    float* hres   = p; p += (size_t)M * 1024;
    float* x_h    = p; p += (size_t)M * 1024 / 2;      // -> Hs after in_proj
    float* x_l    = p; p += (size_t)M * 1024 / 2;
    float* inw_h  = p; p += (size_t)4096 * 1024 / 2;   // -> Pb, then splitK partials
    float* inw_l  = p; p += (size_t)4096 * 1024 / 2;   // -> Hb
    float* xpw_h  = p; p += (size_t)128 * 2048 / 2;    // 96 rows used, padded
    float* xpw_l  = p; p += (size_t)128 * 2048 / 2;
    float* dtw_h  = p; p += (size_t)2048 * 64 / 2;
    float* dtw_l  = p; p += (size_t)2048 * 64 / 2;
    float* ow_h   = p; p += (size_t)1024 * 2048 / 2;
    float* ow_l   = p; p += (size_t)1024 * 2048 / 2;
    float* f1w_h  = p; p += (size_t)2048 * 1024 / 2;
    float* f1w_l  = p; p += (size_t)2048 * 1024 / 2;
    float* f2w_h  = p; p += (size_t)1024 * 2048 / 2;
    float* f2w_l  = p; p += (size_t)1024 * 2048 / 2;

    ushort_t* h_h  = (ushort_t*)xsact_h;   // overlays (regions dead by then)
    ushort_t* h_l  = (ushort_t*)xsact_l;
    ushort_t* f1_h = (ushort_t*)y_h;
    ushort_t* f1_l = (ushort_t*)y_l;
    float* Pb    = inw_h;                  // scan chunk buffers
    float* Hb    = inw_l;
    float* Hs    = x_h;
    float* partX = dtb;                    // x_proj partials (6.3MB < 16MB)
    float* partO = inw_h;                  // out_proj/ffn2 partials (16.8MB fit)

    const dim3 blk(256);

    // ---- batched hi/lo conversion (7 segments, one launch) ----
    CvtArgs ca;
    const float* srcs[NSEG] = {x, in_w, xproj_w, dtproj_w, outw, fw1, fw2};
    ushort_t* his[NSEG] = {(ushort_t*)x_h, (ushort_t*)inw_h, (ushort_t*)xpw_h,
                           (ushort_t*)dtw_h, (ushort_t*)ow_h, (ushort_t*)f1w_h,
                           (ushort_t*)f2w_h};
    ushort_t* los[NSEG] = {(ushort_t*)x_l, (ushort_t*)inw_l, (ushort_t*)xpw_l,
                           (ushort_t*)dtw_l, (ushort_t*)ow_l, (ushort_t*)f1w_l,
                           (ushort_t*)f2w_l};
    const int n4s[NSEG] = {M * 1024 / 4, 4096 * 1024 / 4, 96 * 2048 / 4,
                           2048 * 64 / 4, 1024 * 2048 / 4, 2048 * 1024 / 4,
                           1024 * 2048 / 4};
    int acc4 = 0;
    for (int s = 0; s < NSEG; s++) {
        ca.src[s] = srcs[s]; ca.hi[s] = his[s]; ca.lo[s] = los[s];
        ca.start4[s] = acc4; acc4 += n4s[s];
    }
    ca.total4 = acc4;
    cvt_multi<<<dim3((acc4 + 255) / 256), blk, 0, stream>>>(ca);

    // 1. in_proj: xz = x @ in_w^T   (2048 x 4096 x 1024), 128x64 tiles
    gemm_mfma<0, 128, 64, 1><<<dim3(64, 16, 1), blk, 0, stream>>>(
        (ushort_t*)x_h, (ushort_t*)x_l, 1024,
        (ushort_t*)inw_h, (ushort_t*)inw_l, 1024,
        nullptr, xz, nullptr, nullptr, 4096, 0, 4096, 1024);
    // 2. conv + silu
    conv_silu_kernel<<<dim3(M * DI_ / 4 / 256), blk, 0, stream>>>(
        xz, conv_w, conv_b, xsact, (ushort_t*)xsact_h, (ushort_t*)xsact_l);
    // 3. x_proj: split-K8 partials -> reduce (fp32 + planes)
    gemm_mfma<0, 128, 128, 8><<<dim3(1, 16, 8), blk, 0, stream>>>(
        (ushort_t*)xsact_h, (ushort_t*)xsact_l, 2048,
        (ushort_t*)xpw_h, (ushort_t*)xpw_l, 2048,
        nullptr, partX, nullptr, nullptr, 96, (size_t)M * 96, 96, 2048);
    reduce_k<0, 8><<<dim3((M * 96 / 4 + 255) / 256), blk, 0, stream>>>(
        partX, (size_t)M * 96 / 4, 96, nullptr,
        xdbl, (ushort_t*)xdbl_h, (ushort_t*)xdbl_l);
    // 4. dt = softplus(dt_r @ dt_w^T + b)  (2048 x 2048 x 64)
    gemm_mfma<1, 128, 64, 1><<<dim3(32, 16, 1), blk, 0, stream>>>(
        (ushort_t*)xdbl_h, (ushort_t*)xdbl_l, 96,
        (ushort_t*)dtw_h, (ushort_t*)dtw_l, 64,
        dtproj_b, dtb, nullptr, nullptr, 2048, 0, 2048, 64);
    // 5. chunked scan
    scan_partial<<<dim3(B_ * NCH_ * DI_ / 256), blk, 0, stream>>>(
        dtb, xsact, xdbl, A_log, Pb, Hb);
    scan_fix<<<dim3(B_ * DS_ * DI_ / 256), blk, 0, stream>>>(Pb, Hb, Hs);
    scan_final<<<dim3(B_ * NCH_ * DI_ / 256), blk, 0, stream>>>(
        dtb, xsact, xdbl, xz, Hs, A_log, Dp, (ushort_t*)y_h, (ushort_t*)y_l);
    // 6. out_proj: split-K2 partials -> reduce -> mo
    gemm_mfma<0, 128, 64, 2><<<dim3(16, 16, 2), blk, 0, stream>>>(
        (ushort_t*)y_h, (ushort_t*)y_l, 2048,
        (ushort_t*)ow_h, (ushort_t*)ow_l, 2048,
        nullptr, partO, nullptr, nullptr, 1024, (size_t)M * 1024, 1024, 2048);
    reduce_k<0, 2><<<dim3(M * 1024 / 4 / 256), blk, 0, stream>>>(
        partO, (size_t)M * 1024 / 4, 1024, nullptr, mo, nullptr, nullptr);
    // 7. hres = LN1(mo + x)  (+ planes)
    ln_kernel<<<dim3(M), blk, 0, stream>>>(mo, x, ln1w, ln1b, hres, h_h, h_l);
    // 8. ffn1 + leakyrelu -> f1 planes  (2048 x 2048 x 1024)
    gemm_mfma<2, 128, 64, 1><<<dim3(32, 16, 1), blk, 0, stream>>>(
        h_h, h_l, 1024,
        (ushort_t*)f1w_h, (ushort_t*)f1w_l, 1024,
        fb1, nullptr, f1_h, f1_l, 2048, 0, 2048, 1024);
    // 9. ffn2: split-K2 partials -> reduce(+bias) -> mo
    gemm_mfma<0, 128, 64, 2><<<dim3(16, 16, 2), blk, 0, stream>>>(
        f1_h, f1_l, 2048,
        (ushort_t*)f2w_h, (ushort_t*)f2w_l, 2048,
        nullptr, partO, nullptr, nullptr, 1024, (size_t)M * 1024, 1024, 2048);
    reduce_k<3, 2><<<dim3(M * 1024 / 4 / 256), blk, 0, stream>>>(
        partO, (size_t)M * 1024 / 4, 1024, fb2, mo, nullptr, nullptr);
    // 10. out = LN2(mo + hres)
    ln_kernel<<<dim3(M), blk, 0, stream>>>(mo, hres, ln2w, ln2b, out, nullptr, nullptr);
}

// Round 8
// 652.228 us; speedup vs baseline: 1.6917x; 1.0516x over previous
//
#include <hip/hip_runtime.h>
#include <math.h>

#define B_   4
#define L_   512
#define DM_  1024
#define DS_  16
#define DC_  4
#define DI_  2048
#define DTR_ 64
#define NCH_ 16
#define CHL_ 32   // L_ / NCH_

typedef unsigned short ushort_t;
typedef __attribute__((ext_vector_type(8))) short short8v;
typedef __attribute__((ext_vector_type(4))) float f32x4;

__device__ __forceinline__ ushort_t f2bf(float f) {
    unsigned u = __float_as_uint(f);
    return (ushort_t)((u + 0x7fffu + ((u >> 16) & 1u)) >> 16);
}
__device__ __forceinline__ float bf2f(ushort_t h) {
    return __uint_as_float((unsigned)h << 16);
}

// ---------------------------------------------------------------------------
// Batched fp32 -> (hi, lo) bf16 plane conversion: 7 segments in one launch.
// ---------------------------------------------------------------------------
#define NSEG 7
struct CvtArgs {
    const float* src[NSEG];
    ushort_t*    hi[NSEG];
    ushort_t*    lo[NSEG];
    int start4[NSEG];
    int total4;
};

__global__ __launch_bounds__(256)
void cvt_multi(CvtArgs a)
{
    const int i = blockIdx.x * 256 + threadIdx.x;
    if (i >= a.total4) return;
    int s = 0;
    #pragma unroll
    for (int k = 1; k < NSEG; k++) s += (i >= a.start4[k]) ? 1 : 0;
    const int j = i - a.start4[s];

    const float4 v = ((const float4*)a.src[s])[j];
    const ushort_t h0 = f2bf(v.x), h1 = f2bf(v.y), h2 = f2bf(v.z), h3 = f2bf(v.w);
    ((uint2*)a.hi[s])[j] = make_uint2(h0 | ((unsigned)h1 << 16), h2 | ((unsigned)h3 << 16));
    const ushort_t l0 = f2bf(v.x - bf2f(h0)), l1 = f2bf(v.y - bf2f(h1));
    const ushort_t l2 = f2bf(v.z - bf2f(h2)), l3 = f2bf(v.w - bf2f(h3));
    ((uint2*)a.lo[s])[j] = make_uint2(l0 | ((unsigned)l1 << 16), l2 | ((unsigned)l3 << 16));
}

// ---------------------------------------------------------------------------
// Split-bf16 MFMA GEMM, 2-phase pipelined (double LDS buffer, counted vmcnt,
// raw s_barrier) + XCD-aware block swizzle (each XCD owns contiguous y-rows).
// C[M,N] = A[M,K] @ W[N,K]^T. 4 waves in 2x2, wave tile (BM/2)x(BN/2).
// KS>1 => split-K partials at C + z*pstride (fp32, no epilogue).
// EPI: 0 none, 1 bias+softplus, 2 bias+leakyrelu, 3 bias.
// ---------------------------------------------------------------------------
template<int EPI, int BM, int BN, int KS>
__global__ __launch_bounds__(256, 2)
void gemm_mfma(const ushort_t* __restrict__ Ahi, const ushort_t* __restrict__ Alo, int lda,
               const ushort_t* __restrict__ Whi, const ushort_t* __restrict__ Wlo, int ldw,
               const float* __restrict__ bias,
               float* __restrict__ C, ushort_t* __restrict__ Chi, ushort_t* __restrict__ Clo,
               int ldc, size_t pstride, int N, int K)
{
    constexpr int WM  = BM / 32;
    constexpr int WN  = BN / 32;
    constexpr int PLA = BM * 32;        // ushorts per A plane (one buffer)
    constexpr int PLB = BN * 32;
    constexpr int BUF = 2 * PLA + 2 * PLB;
    __shared__ ushort_t lds[2 * BUF];

    // ---- XCD swizzle: dispatch order (x-fastest) -> y-major chunks per XCD.
    const int nx  = gridDim.x, ny = gridDim.y;
    const int nwg = nx * ny;
    int orig = blockIdx.y * nx + blockIdx.x;
    int wgid = (nwg & 7) == 0 ? ((orig & 7) * (nwg >> 3) + (orig >> 3)) : orig;
    const int bx = wgid % nx;
    const int by = wgid / nx;

    const int t    = threadIdx.x;
    const int lane = t & 63;
    const int wv   = t >> 6;
    const int wm   = (wv >> 1) * (BM / 2);
    const int wn   = (wv & 1) * (BN / 2);
    const int m0   = by * BM;
    const int n0   = bx * BN;
    const int fr   = lane & 15;
    const int fc   = lane >> 4;

    // staging: wave wv owns plane wv (0=Ah 1=Al 2=Wh 3=Wl)
    const int R     = (wv < 2) ? BM : BN;            // rows in my plane
    const int pb    = (wv < 2) ? wv * PLA : 2 * PLA + (wv - 2) * PLB;
    const ushort_t* gbase = (wv == 0) ? Ahi : (wv == 1) ? Alo : (wv == 2) ? Whi : Wlo;
    const int grow0 = ((wv < 2) ? m0 : n0) + lane;
    const int gld   = (wv < 2) ? lda : ldw;
    const int NL    = R >> 6;                        // 64-row groups (1 or 2)

    auto STAGE = [&](int bufi, int k0) {
        for (int c = 0; c < 4; c++)
            for (int h = 0; h < NL; h++) {
                const ushort_t* g = gbase + (size_t)(grow0 + h * 64) * gld + (k0 + c * 8);
                ushort_t* l = &lds[bufi * BUF + pb + (c * R + h * 64) * 8];
                __builtin_amdgcn_global_load_lds(
                    (const __attribute__((address_space(1))) void*)g,
                    (__attribute__((address_space(3))) void*)l, 16, 0, 0);
            }
    };

    f32x4 acc[WM][WN];
    #pragma unroll
    for (int i = 0; i < WM; i++)
        #pragma unroll
        for (int j = 0; j < WN; j++)
            acc[i][j] = (f32x4){0.f, 0.f, 0.f, 0.f};

    const int kbeg = blockIdx.z * (K / KS);
    const int nt   = (K / KS) / 32;

    STAGE(0, kbeg);
    int cur = 0;
    for (int tt = 0; tt < nt; ++tt) {
        if (tt + 1 < nt) {
            STAGE(cur ^ 1, kbeg + (tt + 1) * 32);
            // wait for MY tile-tt loads (tile-tt+1's stay in flight)
            if (R == 128) asm volatile("s_waitcnt vmcnt(8)" ::: "memory");
            else          asm volatile("s_waitcnt vmcnt(4)" ::: "memory");
        } else {
            asm volatile("s_waitcnt vmcnt(0)" ::: "memory");
        }
        __builtin_amdgcn_s_barrier();          // all waves' tile-tt data in LDS
        asm volatile("" ::: "memory");

        const int bb = cur * BUF;
        short8v ah[WM], al[WM];
        #pragma unroll
        for (int i = 0; i < WM; i++) {
            const int ro = fc * BM + wm + i * 16 + fr;
            ah[i] = *(const short8v*)&lds[bb + ro * 8];
            al[i] = *(const short8v*)&lds[bb + PLA + ro * 8];
        }
        #pragma unroll
        for (int j = 0; j < WN; j++) {
            const int ro = fc * BN + wn + j * 16 + fr;
            const short8v bh = *(const short8v*)&lds[bb + 2 * PLA + ro * 8];
            const short8v bl = *(const short8v*)&lds[bb + 2 * PLA + PLB + ro * 8];
            #pragma unroll
            for (int i = 0; i < WM; i++) {
                acc[i][j] = __builtin_amdgcn_mfma_f32_16x16x32_bf16(al[i], bh, acc[i][j], 0, 0, 0);
                acc[i][j] = __builtin_amdgcn_mfma_f32_16x16x32_bf16(ah[i], bl, acc[i][j], 0, 0, 0);
                acc[i][j] = __builtin_amdgcn_mfma_f32_16x16x32_bf16(ah[i], bh, acc[i][j], 0, 0, 0);
            }
        }
        if (tt + 1 < nt) {
            __builtin_amdgcn_s_barrier();      // all reads of buf[cur] done
            asm volatile("" ::: "memory");
        }
        cur ^= 1;
    }

    // ---- epilogue: D row = (lane>>4)*4 + reg, col = lane&15 ----
    if (KS > 1) {
        float* Cp = C + (size_t)blockIdx.z * pstride;
        #pragma unroll
        for (int j = 0; j < WN; j++) {
            const int c = n0 + wn + j * 16 + fr;
            if (c < N) {
                #pragma unroll
                for (int i = 0; i < WM; i++) {
                    const int r = m0 + wm + i * 16 + fc * 4;
                    #pragma unroll
                    for (int q = 0; q < 4; q++)
                        Cp[(size_t)(r + q) * ldc + c] = acc[i][j][q];
                }
            }
        }
        return;
    }
    #pragma unroll
    for (int j = 0; j < WN; j++) {
        const int c = n0 + wn + j * 16 + fr;
        float bj = 0.f;
        if (EPI != 0) bj = bias[c];            // EPI!=0 only with tile-aligned N
        if (c < N) {
            #pragma unroll
            for (int i = 0; i < WM; i++) {
                const int r = m0 + wm + i * 16 + fc * 4;
                #pragma unroll
                for (int q = 0; q < 4; q++) {
                    float v = acc[i][j][q] + bj;
                    if (EPI == 1) v = fmaxf(v, 0.f) + log1pf(expf(-fabsf(v)));
                    else if (EPI == 2) v = (v >= 0.f) ? v : 0.01f * v;
                    const size_t idx = (size_t)(r + q) * ldc + c;
                    if (C) C[idx] = v;
                    if (Chi) {
                        const ushort_t h = f2bf(v);
                        Chi[idx] = h;
                        Clo[idx] = f2bf(v - bf2f(h));
                    }
                }
            }
        }
    }
}

// ---------------------------------------------------------------------------
// Split-K reduce: sum KS fp32 partials, optional bias (EPI==3), write fp32
// and/or hi/lo planes.
// ---------------------------------------------------------------------------
template<int EPI, int KS>
__global__ __launch_bounds__(256)
void reduce_k(const float* __restrict__ part, size_t mn4, int ldc,
              const float* __restrict__ bias,
              float* __restrict__ C, ushort_t* __restrict__ Chi, ushort_t* __restrict__ Clo)
{
    const size_t i = (size_t)blockIdx.x * 256 + threadIdx.x;
    if (i >= mn4) return;
    float4 s = ((const float4*)part)[i];
    #pragma unroll
    for (int z = 1; z < KS; z++) {
        const float4 v = ((const float4*)(part + (size_t)z * mn4 * 4))[i];
        s.x += v.x; s.y += v.y; s.z += v.z; s.w += v.w;
    }
    if (EPI == 3) {
        const int col = (int)((i * 4) % (size_t)ldc);
        const float4 b = *(const float4*)&bias[col];
        s.x += b.x; s.y += b.y; s.z += b.z; s.w += b.w;
    }
    if (C) ((float4*)C)[i] = s;
    if (Chi) {
        const ushort_t h0 = f2bf(s.x), h1 = f2bf(s.y), h2 = f2bf(s.z), h3 = f2bf(s.w);
        ((uint2*)Chi)[i] = make_uint2(h0 | ((unsigned)h1 << 16), h2 | ((unsigned)h3 << 16));
        const ushort_t l0 = f2bf(s.x - bf2f(h0)), l1 = f2bf(s.y - bf2f(h1));
        const ushort_t l2 = f2bf(s.z - bf2f(h2)), l3 = f2bf(s.w - bf2f(h3));
        ((uint2*)Clo)[i] = make_uint2(l0 | ((unsigned)l1 << 16), l2 | ((unsigned)l3 << 16));
    }
}

// ---------------------------------------------------------------------------
// Depthwise causal conv (DC=4) + bias + SiLU; emits fp32 + hi/lo bf16.
// ---------------------------------------------------------------------------
__global__ __launch_bounds__(256)
void conv_silu_kernel(const float* __restrict__ xz,
                      const float* __restrict__ cw,
                      const float* __restrict__ cb,
                      float* __restrict__ xs,
                      ushort_t* __restrict__ xsh, ushort_t* __restrict__ xsl)
{
    const int g   = blockIdx.x * 256 + threadIdx.x;   // quad id
    const int d   = (g & (DI_ / 4 - 1)) * 4;
    const int tok = g >> 9;
    const int l   = tok & (L_ - 1);
    const int t0  = tok - l;
    const float4 w0 = *(const float4*)&cw[(d + 0) * 4];
    const float4 w1 = *(const float4*)&cw[(d + 1) * 4];
    const float4 w2 = *(const float4*)&cw[(d + 2) * 4];
    const float4 w3 = *(const float4*)&cw[(d + 3) * 4];
    float4 s = *(const float4*)&cb[d];
    if (l >= 3) { const float4 v = *(const float4*)&xz[(size_t)(t0 + l - 3) * (2 * DI_) + d];
        s.x += w0.x * v.x; s.y += w1.x * v.y; s.z += w2.x * v.z; s.w += w3.x * v.w; }
    if (l >= 2) { const float4 v = *(const float4*)&xz[(size_t)(t0 + l - 2) * (2 * DI_) + d];
        s.x += w0.y * v.x; s.y += w1.y * v.y; s.z += w2.y * v.z; s.w += w3.y * v.w; }
    if (l >= 1) { const float4 v = *(const float4*)&xz[(size_t)(t0 + l - 1) * (2 * DI_) + d];
        s.x += w0.z * v.x; s.y += w1.z * v.y; s.z += w2.z * v.z; s.w += w3.z * v.w; }
    {           const float4 v = *(const float4*)&xz[(size_t)(t0 + l) * (2 * DI_) + d];
        s.x += w0.w * v.x; s.y += w1.w * v.y; s.z += w2.w * v.z; s.w += w3.w * v.w; }
    s.x = s.x / (1.f + __expf(-s.x));
    s.y = s.y / (1.f + __expf(-s.y));
    s.z = s.z / (1.f + __expf(-s.z));
    s.w = s.w / (1.f + __expf(-s.w));
    const size_t off = (size_t)tok * DI_ + d;
    *(float4*)&xs[off] = s;
    const ushort_t h0 = f2bf(s.x), h1 = f2bf(s.y), h2 = f2bf(s.z), h3 = f2bf(s.w);
    *(uint2*)&xsh[off] = make_uint2(h0 | ((unsigned)h1 << 16), h2 | ((unsigned)h3 << 16));
    const ushort_t l0 = f2bf(s.x - bf2f(h0)), l1 = f2bf(s.y - bf2f(h1));
    const ushort_t l2 = f2bf(s.z - bf2f(h2)), l3 = f2bf(s.w - bf2f(h3));
    *(uint2*)&xsl[off] = make_uint2(l0 | ((unsigned)l1 << 16), l2 | ((unsigned)l3 << 16));
}

// ---------------------------------------------------------------------------
// Chunked selective scan (no cross-lane ops): partial -> fix -> final.
// ---------------------------------------------------------------------------
__global__ __launch_bounds__(256)
void scan_partial(const float* __restrict__ dt, const float* __restrict__ xs,
                  const float* __restrict__ xdbl, const float* __restrict__ A_log,
                  float* __restrict__ Pb, float* __restrict__ Hb)
{
    const int g  = blockIdx.x * 256 + threadIdx.x;   // (b*NCH+c)*DI + d
    const int d  = g & (DI_ - 1);
    const int bc = g >> 11;
    const int tok0 = (bc >> 4) * L_ + (bc & (NCH_ - 1)) * CHL_;

    float a[DS_], h[DS_], P[DS_];
    #pragma unroll
    for (int n = 0; n < DS_; n++) {
        a[n] = -expf(A_log[d * DS_ + n]);
        h[n] = 0.f; P[n] = 1.f;
    }

    #pragma unroll 1
    for (int l = 0; l < CHL_; l++) {
        const size_t tok = tok0 + l;
        const float dtv = dt[tok * DI_ + d];
        const float xv  = xs[tok * DI_ + d];
        const float dbx = dtv * xv;
        const float* bp = xdbl + tok * 96 + 64;
        const float4 B0 = *(const float4*)(bp + 0);
        const float4 B1 = *(const float4*)(bp + 4);
        const float4 B2 = *(const float4*)(bp + 8);
        const float4 B3 = *(const float4*)(bp + 12);
        const float Bv[DS_] = {B0.x,B0.y,B0.z,B0.w, B1.x,B1.y,B1.z,B1.w,
                               B2.x,B2.y,B2.z,B2.w, B3.x,B3.y,B3.z,B3.w};
        #pragma unroll
        for (int n = 0; n < DS_; n++) {
            const float dA = __expf(dtv * a[n]);
            h[n] = fmaf(dA, h[n], dbx * Bv[n]);
            P[n] *= dA;
        }
    }
    #pragma unroll
    for (int n = 0; n < DS_; n++) {
        const size_t idx = ((size_t)bc * DS_ + n) * DI_ + d;
        Pb[idx] = P[n];
        Hb[idx] = h[n];
    }
}

__global__ __launch_bounds__(256)
void scan_fix(const float* __restrict__ Pb, const float* __restrict__ Hb,
              float* __restrict__ Hs)
{
    const int g  = blockIdx.x * 256 + threadIdx.x;   // (b*16+n)*DI + d
    const int d  = g & (DI_ - 1);
    const int bn = g >> 11;
    const int b  = bn >> 4;
    const int n  = bn & (DS_ - 1);
    float hs = 0.f;
    #pragma unroll 1
    for (int c = 0; c < NCH_; c++) {
        const size_t idx = ((size_t)(b * NCH_ + c) * DS_ + n) * DI_ + d;
        Hs[idx] = hs;
        hs = fmaf(Pb[idx], hs, Hb[idx]);
    }
}

__global__ __launch_bounds__(256)
void scan_final(const float* __restrict__ dt, const float* __restrict__ xs,
                const float* __restrict__ xdbl, const float* __restrict__ xz,
                const float* __restrict__ Hs, const float* __restrict__ A_log,
                const float* __restrict__ Dp,
                ushort_t* __restrict__ yh, ushort_t* __restrict__ yl)
{
    const int g  = blockIdx.x * 256 + threadIdx.x;   // (b*NCH+c)*DI + d
    const int d  = g & (DI_ - 1);
    const int bc = g >> 11;
    const int tok0 = (bc >> 4) * L_ + (bc & (NCH_ - 1)) * CHL_;
    const float Dd = Dp[d];

    float a[DS_], h[DS_];
    #pragma unroll
    for (int n = 0; n < DS_; n++) {
        a[n] = -expf(A_log[d * DS_ + n]);
        h[n] = Hs[((size_t)bc * DS_ + n) * DI_ + d];
    }

    #pragma unroll 1
    for (int l = 0; l < CHL_; l++) {
        const size_t tok = tok0 + l;
        const float dtv = dt[tok * DI_ + d];
        const float xv  = xs[tok * DI_ + d];
        const float zv  = xz[tok * (2 * DI_) + DI_ + d];
        const float dbx = dtv * xv;
        const float* bp = xdbl + tok * 96 + 64;
        const float4 B0 = *(const float4*)(bp + 0);
        const float4 B1 = *(const float4*)(bp + 4);
        const float4 B2 = *(const float4*)(bp + 8);
        const float4 B3 = *(const float4*)(bp + 12);
        const float4 C0 = *(const float4*)(bp + 16);
        const float4 C1 = *(const float4*)(bp + 20);
        const float4 C2 = *(const float4*)(bp + 24);
        const float4 C3 = *(const float4*)(bp + 28);
        const float Bv[DS_] = {B0.x,B0.y,B0.z,B0.w, B1.x,B1.y,B1.z,B1.w,
                               B2.x,B2.y,B2.z,B2.w, B3.x,B3.y,B3.z,B3.w};
        const float Cv[DS_] = {C0.x,C0.y,C0.z,C0.w, C1.x,C1.y,C1.z,C1.w,
                               C2.x,C2.y,C2.z,C2.w, C3.x,C3.y,C3.z,C3.w};
        float acc = 0.f;
        #pragma unroll
        for (int n = 0; n < DS_; n++) {
            const float dA = __expf(dtv * a[n]);
            h[n] = fmaf(dA, h[n], dbx * Bv[n]);
            acc  = fmaf(h[n], Cv[n], acc);
        }
        const float sz = zv / (1.f + __expf(-zv));
        const float yv = fmaf(Dd, xv, acc) * sz;
        const size_t idx = tok * DI_ + d;
        const ushort_t hh = f2bf(yv);
        yh[idx] = hh;
        yl[idx] = f2bf(yv - bf2f(hh));
    }
}

// ---------------------------------------------------------------------------
// out = LN(a + r) * w + b ; optional hi/lo bf16 planes. One block per token.
// ---------------------------------------------------------------------------
__global__ __launch_bounds__(256)
void ln_kernel(const float* __restrict__ a, const float* __restrict__ r,
               const float* __restrict__ w, const float* __restrict__ b,
               float* __restrict__ out,
               ushort_t* __restrict__ oh, ushort_t* __restrict__ ol)
{
    const int tok = blockIdx.x;
    const int tid = threadIdx.x;
    const size_t off = (size_t)tok * DM_ + tid * 4;
    const float4 va = *(const float4*)&a[off];
    const float4 vr = *(const float4*)&r[off];
    const float xv[4] = {va.x + vr.x, va.y + vr.y, va.z + vr.z, va.w + vr.w};

    float s  = xv[0] + xv[1] + xv[2] + xv[3];
    float sq = xv[0]*xv[0] + xv[1]*xv[1] + xv[2]*xv[2] + xv[3]*xv[3];
    #pragma unroll
    for (int o = 32; o > 0; o >>= 1) {
        s  += __shfl_xor(s,  o, 64);
        sq += __shfl_xor(sq, o, 64);
    }
    __shared__ float ss[4], sqs[4];
    const int wid = tid >> 6;
    if ((tid & 63) == 0) { ss[wid] = s; sqs[wid] = sq; }
    __syncthreads();
    s  = ss[0] + ss[1] + ss[2] + ss[3];
    sq = sqs[0] + sqs[1] + sqs[2] + sqs[3];

    const float mean = s * (1.f / DM_);
    const float var  = sq * (1.f / DM_) - mean * mean;
    const float rs   = rsqrtf(var + 1e-12f);

    const float4 vw = *(const float4*)&w[tid * 4];
    const float4 vb = *(const float4*)&b[tid * 4];
    const float o0 = (xv[0] - mean) * rs * vw.x + vb.x;
    const float o1 = (xv[1] - mean) * rs * vw.y + vb.y;
    const float o2 = (xv[2] - mean) * rs * vw.z + vb.z;
    const float o3 = (xv[3] - mean) * rs * vw.w + vb.w;
    *(float4*)&out[off] = make_float4(o0, o1, o2, o3);
    if (oh) {
        const ushort_t h0 = f2bf(o0), h1 = f2bf(o1), h2 = f2bf(o2), h3 = f2bf(o3);
        *(uint2*)&oh[off] = make_uint2(h0 | ((unsigned)h1 << 16), h2 | ((unsigned)h3 << 16));
        const ushort_t l0 = f2bf(o0 - bf2f(h0)), l1 = f2bf(o1 - bf2f(h1));
        const ushort_t l2 = f2bf(o2 - bf2f(h2)), l3 = f2bf(o3 - bf2f(h3));
        *(uint2*)&ol[off] = make_uint2(l0 | ((unsigned)l1 << 16), l2 | ((unsigned)l3 << 16));
    }
}

// ---------------------------------------------------------------------------
extern "C" void kernel_launch(void* const* d_in, const int* in_sizes, int n_in,
                              void* d_out, int out_size, void* d_ws, size_t ws_size,
                              hipStream_t stream)
{
    const float* x        = (const float*)d_in[0];
    const float* in_w     = (const float*)d_in[1];
    const float* conv_w   = (const float*)d_in[2];
    const float* conv_b   = (const float*)d_in[3];
    const float* xproj_w  = (const float*)d_in[4];
    const float* dtproj_w = (const float*)d_in[5];
    const float* dtproj_b = (const float*)d_in[6];
    const float* A_log    = (const float*)d_in[7];
    const float* Dp       = (const float*)d_in[8];
    const float* outw     = (const float*)d_in[9];
    const float* ln1w     = (const float*)d_in[10];
    const float* ln1b     = (const float*)d_in[11];
    const float* fw1      = (const float*)d_in[12];
    const float* fb1      = (const float*)d_in[13];
    const float* fw2      = (const float*)d_in[14];
    const float* fb2      = (const float*)d_in[15];
    const float* ln2w     = (const float*)d_in[16];
    const float* ln2b     = (const float*)d_in[17];
    float* out = (float*)d_out;

    const int M = B_ * L_;   // 2048
    // ---- workspace carve (floats). total ~171 MB ----
    float* p = (float*)d_ws;
    float* xz     = p; p += (size_t)M * 4096;
    float* xsact  = p; p += (size_t)M * 2048;
    float* xsact_h= p; p += (size_t)M * 2048 / 2;
    float* xsact_l= p; p += (size_t)M * 2048 / 2;
    float* xdbl   = p; p += (size_t)M * 96;
    float* xdbl_h = p; p += (size_t)M * 96 / 2;
    float* xdbl_l = p; p += (size_t)M * 96 / 2;
    float* dtb    = p; p += (size_t)M * 2048;          // also x_proj split-K partials
    float* y_h    = p; p += (size_t)M * 2048 / 2;
    float* y_l    = p; p += (size_t)M * 2048 / 2;
    float* mo     = p; p += (size_t)M * 1024;
    float* hres   = p; p += (size_t)M * 1024;
    float* x_h    = p; p += (size_t)M * 1024 / 2;      // -> Hs after in_proj
    float* x_l    = p; p += (size_t)M * 1024 / 2;
    float* inw_h  = p; p += (size_t)4096 * 1024 / 2;   // -> Pb, then splitK partials
    float* inw_l  = p; p += (size_t)4096 * 1024 / 2;   // -> Hb
    float* xpw_h  = p; p += (size_t)128 * 2048 / 2;    // 96 rows used, padded
    float* xpw_l  = p; p += (size_t)128 * 2048 / 2;
    float* dtw_h  = p; p += (size_t)2048 * 64 / 2;
    float* dtw_l  = p; p += (size_t)2048 * 64 / 2;
    float* ow_h   = p; p += (size_t)1024 * 2048 / 2;
    float* ow_l   = p; p += (size_t)1024 * 2048 / 2;
    float* f1w_h  = p; p += (size_t)2048 * 1024 / 2;
    float* f1w_l  = p; p += (size_t)2048 * 1024 / 2;
    float* f2w_h  = p; p += (size_t)1024 * 2048 / 2;
    float* f2w_l  = p; p += (size_t)1024 * 2048 / 2;

    ushort_t* h_h  = (ushort_t*)xsact_h;   // overlays (regions dead by then)
    ushort_t* h_l  = (ushort_t*)xsact_l;
    ushort_t* f1_h = (ushort_t*)y_h;
    ushort_t* f1_l = (ushort_t*)y_l;
    float* Pb    = inw_h;                  // scan chunk buffers
    float* Hb    = inw_l;
    float* Hs    = x_h;
    float* partX = dtb;                    // x_proj partials (6.3MB < 16MB)
    float* partO = inw_h;                  // out_proj/ffn2 partials (16.8MB fit)

    const dim3 blk(256);

    // ---- batched hi/lo conversion (7 segments, one launch) ----
    CvtArgs ca;
    const float* srcs[NSEG] = {x, in_w, xproj_w, dtproj_w, outw, fw1, fw2};
    ushort_t* his[NSEG] = {(ushort_t*)x_h, (ushort_t*)inw_h, (ushort_t*)xpw_h,
                           (ushort_t*)dtw_h, (ushort_t*)ow_h, (ushort_t*)f1w_h,
                           (ushort_t*)f2w_h};
    ushort_t* los[NSEG] = {(ushort_t*)x_l, (ushort_t*)inw_l, (ushort_t*)xpw_l,
                           (ushort_t*)dtw_l, (ushort_t*)ow_l, (ushort_t*)f1w_l,
                           (ushort_t*)f2w_l};
    const int n4s[NSEG] = {M * 1024 / 4, 4096 * 1024 / 4, 96 * 2048 / 4,
                           2048 * 64 / 4, 1024 * 2048 / 4, 2048 * 1024 / 4,
                           1024 * 2048 / 4};
    int acc4 = 0;
    for (int s = 0; s < NSEG; s++) {
        ca.src[s] = srcs[s]; ca.hi[s] = his[s]; ca.lo[s] = los[s];
        ca.start4[s] = acc4; acc4 += n4s[s];
    }
    ca.total4 = acc4;
    cvt_multi<<<dim3((acc4 + 255) / 256), blk, 0, stream>>>(ca);

    // 1. in_proj: xz = x @ in_w^T   (2048 x 4096 x 1024), 128x128 + swizzle
    gemm_mfma<0, 128, 128, 1><<<dim3(32, 16, 1), blk, 0, stream>>>(
        (ushort_t*)x_h, (ushort_t*)x_l, 1024,
        (ushort_t*)inw_h, (ushort_t*)inw_l, 1024,
        nullptr, xz, nullptr, nullptr, 4096, 0, 4096, 1024);
    // 2. conv + silu
    conv_silu_kernel<<<dim3(M * DI_ / 4 / 256), blk, 0, stream>>>(
        xz, conv_w, conv_b, xsact, (ushort_t*)xsact_h, (ushort_t*)xsact_l);
    // 3. x_proj: split-K8 partials -> reduce (fp32 + planes)
    gemm_mfma<0, 128, 128, 8><<<dim3(1, 16, 8), blk, 0, stream>>>(
        (ushort_t*)xsact_h, (ushort_t*)xsact_l, 2048,
        (ushort_t*)xpw_h, (ushort_t*)xpw_l, 2048,
        nullptr, partX, nullptr, nullptr, 96, (size_t)M * 96, 96, 2048);
    reduce_k<0, 8><<<dim3((M * 96 / 4 + 255) / 256), blk, 0, stream>>>(
        partX, (size_t)M * 96 / 4, 96, nullptr,
        xdbl, (ushort_t*)xdbl_h, (ushort_t*)xdbl_l);
    // 4. dt = softplus(dt_r @ dt_w^T + b)  (2048 x 2048 x 64)
    gemm_mfma<1, 128, 64, 1><<<dim3(32, 16, 1), blk, 0, stream>>>(
        (ushort_t*)xdbl_h, (ushort_t*)xdbl_l, 96,
        (ushort_t*)dtw_h, (ushort_t*)dtw_l, 64,
        dtproj_b, dtb, nullptr, nullptr, 2048, 0, 2048, 64);
    // 5. chunked scan
    scan_partial<<<dim3(B_ * NCH_ * DI_ / 256), blk, 0, stream>>>(
        dtb, xsact, xdbl, A_log, Pb, Hb);
    scan_fix<<<dim3(B_ * DS_ * DI_ / 256), blk, 0, stream>>>(Pb, Hb, Hs);
    scan_final<<<dim3(B_ * NCH_ * DI_ / 256), blk, 0, stream>>>(
        dtb, xsact, xdbl, xz, Hs, A_log, Dp, (ushort_t*)y_h, (ushort_t*)y_l);
    // 6. out_proj: split-K2 partials -> reduce -> mo
    gemm_mfma<0, 128, 64, 2><<<dim3(16, 16, 2), blk, 0, stream>>>(
        (ushort_t*)y_h, (ushort_t*)y_l, 2048,
        (ushort_t*)ow_h, (ushort_t*)ow_l, 2048,
        nullptr, partO, nullptr, nullptr, 1024, (size_t)M * 1024, 1024, 2048);
    reduce_k<0, 2><<<dim3(M * 1024 / 4 / 256), blk, 0, stream>>>(
        partO, (size_t)M * 1024 / 4, 1024, nullptr, mo, nullptr, nullptr);
    // 7. hres = LN1(mo + x)  (+ planes)
    ln_kernel<<<dim3(M), blk, 0, stream>>>(mo, x, ln1w, ln1b, hres, h_h, h_l);
    // 8. ffn1 + leakyrelu -> f1 planes  (2048 x 2048 x 1024), 128x128 + swizzle
    gemm_mfma<2, 128, 128, 1><<<dim3(16, 16, 1), blk, 0, stream>>>(
        h_h, h_l, 1024,
        (ushort_t*)f1w_h, (ushort_t*)f1w_l, 1024,
        fb1, nullptr, f1_h, f1_l, 2048, 0, 2048, 1024);
    // 9. ffn2: split-K2 partials -> reduce(+bias) -> mo
    gemm_mfma<0, 128, 64, 2><<<dim3(16, 16, 2), blk, 0, stream>>>(
        f1_h, f1_l, 2048,
        (ushort_t*)f2w_h, (ushort_t*)f2w_l, 2048,
        nullptr, partO, nullptr, nullptr, 1024, (size_t)M * 1024, 1024, 2048);
    reduce_k<3, 2><<<dim3(M * 1024 / 4 / 256), blk, 0, stream>>>(
        partO, (size_t)M * 1024 / 4, 1024, fb2, mo, nullptr, nullptr);
    // 10. out = LN2(mo + hres)
    ln_kernel<<<dim3(M), blk, 0, stream>>>(mo, hres, ln2w, ln2b, out, nullptr, nullptr);
}